// Round 2
// baseline (1543.915 us; speedup 1.0000x reference)
//
#include <hip/hip_runtime.h>
#include <cstdint>
#include <cstddef>

#define HNUM 8
#define HDIM 64
#define WIN 512
#define RATIO 8
#define TOPKN 64
#define BATCH 2
#define SEQ 2048
#define DM 512
#define NPOOLS 192
#define NEGV (-1000000000.0f)

typedef unsigned short u16;
typedef __attribute__((ext_vector_type(8))) short bf16x8;
typedef __attribute__((ext_vector_type(4))) float f32x4;

static __device__ __forceinline__ int imaxi(int a, int b){ return a > b ? a : b; }

// bf16 round-to-nearest-even via bit ops (inputs are finite; NaN path irrelevant)
static __device__ __forceinline__ u16 f2bf(float v) {
    union { float f; uint32_t u; } c; c.f = v;
    uint32_t r = c.u + 0x7fffu + ((c.u >> 16) & 1u);
    return (u16)(r >> 16);
}
static __device__ __forceinline__ float bf2f(u16 u) {
    union { uint32_t u; float f; } c; c.u = ((uint32_t)u) << 16;
    return c.f;
}

// ---------------- fp32 -> (hi, lo) bf16 planes, elementwise ----------------
__global__ __launch_bounds__(256)
void conv_act(const float* __restrict__ in, u16* __restrict__ h, u16* __restrict__ l, int n8)
{
    int i = blockIdx.x * 256 + threadIdx.x;
    if (i >= n8) return;
    const float4* p = (const float4*)(in + (size_t)i * 8);
    float4 a = p[0], b = p[1];
    float v[8] = {a.x, a.y, a.z, a.w, b.x, b.y, b.z, b.w};
    u16 hs[8], ls[8];
    #pragma unroll
    for (int j = 0; j < 8; ++j) {
        hs[j] = f2bf(v[j]);
        ls[j] = f2bf(v[j] - bf2f(hs[j]));
    }
    *(uint4*)(h + (size_t)i * 8) = *(uint4*)hs;
    *(uint4*)(l + (size_t)i * 8) = *(uint4*)ls;
}

// ------------- weight transpose-convert: W[512][N] -> WT planes [N][512] -------------
__global__ __launch_bounds__(256)
void conv_wT(const float* __restrict__ W, int N,
             u16* __restrict__ WTh, u16* __restrict__ WTl, int dstRowOff)
{
    __shared__ float t[64][65];
    const int n0 = blockIdx.x * 64, k0 = blockIdx.y * 64;
    const int tid = threadIdx.x;
    const int tk = tid >> 4, tn = (tid & 15) * 4;
    #pragma unroll
    for (int r = 0; r < 4; ++r) {
        int k = tk + r * 16;
        float4 v = *(const float4*)(W + (size_t)(k0 + k) * N + n0 + tn);
        t[k][tn + 0] = v.x; t[k][tn + 1] = v.y; t[k][tn + 2] = v.z; t[k][tn + 3] = v.w;
    }
    __syncthreads();
    const int nl = tid >> 2, s = tid & 3;
    u16 hs[16], ls[16];
    #pragma unroll
    for (int j = 0; j < 16; ++j) {
        float v = t[s * 16 + j][nl];
        hs[j] = f2bf(v);
        ls[j] = f2bf(v - bf2f(hs[j]));
    }
    size_t base = (size_t)(dstRowOff + n0 + nl) * 512 + k0 + s * 16;
    *(uint4*)(WTh + base)     = ((uint4*)hs)[0];
    *(uint4*)(WTh + base + 8) = ((uint4*)hs)[1];
    *(uint4*)(WTl + base)     = ((uint4*)ls)[0];
    *(uint4*)(WTl + base + 8) = ((uint4*)ls)[1];
}

// ---------------- bias concat for fused q/gate GEMM ----------------
__global__ void bcat_fill(const float* __restrict__ b0, const float* __restrict__ b1,
                          const float* __restrict__ b2, const float* __restrict__ b3,
                          float* __restrict__ bcat)
{
    int i = blockIdx.x * 256 + threadIdx.x;
    if (i < 512) bcat[i] = b0[i];
    else if (i < 1024) bcat[i] = b1[i - 512];
    else if (i < 1536) bcat[i] = b2[i - 1024];
    else if (i < 2048) bcat[i] = b3[i - 1536];
}

// ---------------- split-bf16 MFMA GEMM: M=4096, K=512 ----------------
// C = A@B + bias   (MODE 0)   |   C += sigmoid(G) * (A@B + bias)  (MODE 1)
// A given as hi/lo bf16 planes [M][512]; B as transposed planes [N][512].
// Tile 128x64, BK=32, 4 waves (each 64x32 = 4x2 16x16 frags), 3 MFMA per frag (hh, hl, lh).
template<int MODE>
__global__ __launch_bounds__(256)
void gemm_mfma(const u16* __restrict__ Ah, const u16* __restrict__ Al,
               const u16* __restrict__ BTh, const u16* __restrict__ BTl,
               const float* __restrict__ bias, float* __restrict__ C,
               const float* __restrict__ G, int gstride, int N)
{
    // padded row stride 40 ushorts (80B): rows land on 8 distinct banks, ~2-way conflicts
    __shared__ __align__(16) u16 AsH[128 * 40], AsL[128 * 40], BsH[64 * 40], BsL[64 * 40];
    const int tid = threadIdx.x;
    const int m0 = blockIdx.y * 128, n0 = blockIdx.x * 64;
    const int wid = tid >> 6, lane = tid & 63;
    const int wm = (wid >> 1) * 64, wn = (wid & 1) * 32;
    const int lr = lane & 15, lg = lane >> 4;

    f32x4 acc[4][2];
    #pragma unroll
    for (int i = 0; i < 4; ++i)
        #pragma unroll
        for (int j = 0; j < 2; ++j) acc[i][j] = (f32x4){0.f, 0.f, 0.f, 0.f};

    const int r0 = tid >> 2, s = tid & 3;   // staging: row, 16B slot

    for (int k0 = 0; k0 < 512; k0 += 32) {
        __syncthreads();   // protect LDS against previous iteration's readers
        size_t ga = (size_t)(m0 + r0) * 512 + k0 + s * 8;
        *(uint4*)&AsH[r0 * 40 + s * 8] = *(const uint4*)(Ah + ga);
        *(uint4*)&AsL[r0 * 40 + s * 8] = *(const uint4*)(Al + ga);
        size_t gb = (size_t)(m0 + r0 + 64) * 512 + k0 + s * 8;
        *(uint4*)&AsH[(r0 + 64) * 40 + s * 8] = *(const uint4*)(Ah + gb);
        *(uint4*)&AsL[(r0 + 64) * 40 + s * 8] = *(const uint4*)(Al + gb);
        size_t gc = (size_t)(n0 + r0) * 512 + k0 + s * 8;
        *(uint4*)&BsH[r0 * 40 + s * 8] = *(const uint4*)(BTh + gc);
        *(uint4*)&BsL[r0 * 40 + s * 8] = *(const uint4*)(BTl + gc);
        __syncthreads();

        bf16x8 ah[4], al[4], bh[2], bl[2];
        #pragma unroll
        for (int i = 0; i < 4; ++i) {
            int row = wm + i * 16 + lr;
            ah[i] = *(const bf16x8*)&AsH[row * 40 + lg * 8];
            al[i] = *(const bf16x8*)&AsL[row * 40 + lg * 8];
        }
        #pragma unroll
        for (int j = 0; j < 2; ++j) {
            int row = wn + j * 16 + lr;
            bh[j] = *(const bf16x8*)&BsH[row * 40 + lg * 8];
            bl[j] = *(const bf16x8*)&BsL[row * 40 + lg * 8];
        }
        #pragma unroll
        for (int i = 0; i < 4; ++i)
            #pragma unroll
            for (int j = 0; j < 2; ++j) {
                acc[i][j] = __builtin_amdgcn_mfma_f32_16x16x32_bf16(ah[i], bh[j], acc[i][j], 0, 0, 0);
                acc[i][j] = __builtin_amdgcn_mfma_f32_16x16x32_bf16(ah[i], bl[j], acc[i][j], 0, 0, 0);
                acc[i][j] = __builtin_amdgcn_mfma_f32_16x16x32_bf16(al[i], bh[j], acc[i][j], 0, 0, 0);
            }
    }

    // epilogue: D row = (lane>>4)*4 + reg, col = lane&15  [m89-verified layout]
    #pragma unroll
    for (int i = 0; i < 4; ++i)
        #pragma unroll
        for (int j = 0; j < 2; ++j) {
            int col = n0 + wn + j * 16 + lr;
            float bs = bias[col];
            #pragma unroll
            for (int r = 0; r < 4; ++r) {
                int row = m0 + wm + i * 16 + lg * 4 + r;
                float v = acc[i][j][r] + bs;
                size_t idx = (size_t)row * N + col;
                if (MODE == 0) C[idx] = v;
                else {
                    float g = G[(size_t)row * gstride + col];
                    C[idx] += v / (1.0f + __expf(-g));
                }
            }
        }
}

// ---------------- fp32 vector GEMM for the small matrices (K=512, BN=64, BM=16*TM) ----------------
template<int TM>
__global__ __launch_bounds__(256)
void gemm_k512(const float* __restrict__ A, const float* __restrict__ W,
               const float* __restrict__ bias, float* __restrict__ C,
               int M, int N)
{
    constexpr int BM = TM * 16;
    constexpr int BK = 32;
    __shared__ float As[BK][BM + 4];
    __shared__ float Bs[BK][64 + 4];
    const int tid = threadIdx.x;
    const int m0 = blockIdx.y * BM;
    const int n0 = blockIdx.x * 64;
    const int tm = tid >> 4, tn = tid & 15;
    float acc[TM][4];
    #pragma unroll
    for (int i = 0; i < TM; ++i)
        #pragma unroll
        for (int j = 0; j < 4; ++j) acc[i][j] = 0.f;

    for (int k0 = 0; k0 < 512; k0 += BK) {
        #pragma unroll
        for (int f = tid; f < BM * 8; f += 256) {
            int row = f >> 3, c4 = f & 7;
            float4 av = *(const float4*)(A + (size_t)(m0 + row) * 512 + k0 + c4 * 4);
            As[c4 * 4 + 0][row] = av.x;
            As[c4 * 4 + 1][row] = av.y;
            As[c4 * 4 + 2][row] = av.z;
            As[c4 * 4 + 3][row] = av.w;
        }
        #pragma unroll
        for (int f = tid; f < 512; f += 256) {
            int row = f >> 4, c4 = f & 15;
            *(float4*)(&Bs[row][c4 * 4]) = *(const float4*)(W + (size_t)(k0 + row) * N + n0 + c4 * 4);
        }
        __syncthreads();
        #pragma unroll
        for (int kk = 0; kk < BK; ++kk) {
            float a[TM], bb[4];
            #pragma unroll
            for (int i4 = 0; i4 < TM / 4; ++i4)
                *(float4*)(&a[i4 * 4]) = *(const float4*)(&As[kk][tm * TM + i4 * 4]);
            *(float4*)(bb) = *(const float4*)(&Bs[kk][tn * 4]);
            #pragma unroll
            for (int i = 0; i < TM; ++i)
                #pragma unroll
                for (int j = 0; j < 4; ++j)
                    acc[i][j] += a[i] * bb[j];
        }
        __syncthreads();
    }
    #pragma unroll
    for (int i = 0; i < TM; ++i) {
        int m = m0 + tm * TM + i;
        #pragma unroll
        for (int j = 0; j < 4; ++j) {
            int n = n0 + tn * 4 + j;
            C[(size_t)m * N + n] = acc[i][j] + bias[n];
        }
    }
}

// ---------------- mean-pool x over groups of 8 tokens (first 1536) ----------------
__global__ void pool_x(const float* __restrict__ x, float* __restrict__ comp)
{
    int row = blockIdx.x;          // 0..383
    int b = row / NPOOLS, p = row % NPOOLS;
    const float* src = x + ((size_t)b * SEQ + (size_t)p * RATIO) * DM;
    float* dst = comp + (size_t)row * DM;
    for (int d = threadIdx.x; d < DM; d += 256) {
        float sv = 0.f;
        #pragma unroll
        for (int r = 0; r < RATIO; ++r) sv += src[(size_t)r * DM + d];
        dst[d] = sv * 0.125f;
    }
}

// ---------------- importance GEMV ----------------
__global__ __launch_bounds__(256)
void gemv_imp(const float* __restrict__ x, const float* __restrict__ w,
              const float* __restrict__ bsc, float* __restrict__ imp)
{
    int row = blockIdx.x * 4 + (threadIdx.x >> 6);
    int lane = threadIdx.x & 63;
    const float* xr = x + (size_t)row * DM;
    float sv = 0.f;
    #pragma unroll
    for (int i = 0; i < 8; ++i) sv += xr[lane + i * 64] * w[lane + i * 64];
    #pragma unroll
    for (int off = 32; off; off >>= 1) sv += __shfl_xor(sv, off);
    if (lane == 0) imp[row] = sv + bsc[0];
}

// ---------------- top-64 per batch (iterative argmax, lowest index on ties) ----------------
__global__ __launch_bounds__(64)
void topk_sel(const float* __restrict__ imp, int* __restrict__ tidx)
{
    __shared__ float vals[SEQ];
    int b = blockIdx.x;
    int lane = threadIdx.x;
    for (int i = lane; i < SEQ; i += 64) vals[i] = imp[(size_t)b * SEQ + i];
    __syncthreads();
    for (int r = 0; r < TOPKN; ++r) {
        float bv = -1e30f; int bi = 0x7fffffff;
        for (int i = lane; i < SEQ; i += 64) {
            float v = vals[i];
            if (v > bv) { bv = v; bi = i; }
        }
        #pragma unroll
        for (int off = 32; off; off >>= 1) {
            float ov = __shfl_xor(bv, off);
            int oi = __shfl_xor(bi, off);
            if (ov > bv || (ov == bv && oi < bi)) { bv = ov; bi = oi; }
        }
        if (lane == 0) {
            tidx[b * TOPKN + r] = bi;
            vals[bi] = -1e30f;
        }
        __syncthreads();
    }
}

// ---------------- gather selected rows of x ----------------
__global__ void gather_sel(const float* __restrict__ x, const int* __restrict__ tidx,
                           float* __restrict__ sel)
{
    int r = blockIdx.x;            // 0..127
    int b = r >> 6;
    int t = tidx[r];
    const float* src = x + ((size_t)b * SEQ + t) * DM;
    float* dst = sel + (size_t)r * DM;
    for (int j = threadIdx.x; j < DM; j += 256) dst[j] = src[j];
}

// ---------------- attention: one thread per query; emit hi/lo bf16 planes ----------------
static __device__ __forceinline__ void store_o_planes(const float* o, float inv,
                                                      u16* oh, u16* ol, size_t base)
{
    #pragma unroll
    for (int d0 = 0; d0 < 8; ++d0) {
        u16 hs[8], ls[8];
        #pragma unroll
        for (int j = 0; j < 8; ++j) {
            float v = o[d0 * 8 + j] * inv;
            hs[j] = f2bf(v);
            ls[j] = f2bf(v - bf2f(hs[j]));
        }
        *(uint4*)(oh + base + d0 * 8) = *(uint4*)hs;
        *(uint4*)(ol + base + d0 * 8) = *(uint4*)ls;
    }
}

__global__ __launch_bounds__(64)
void attn_local_k(const float* __restrict__ qkv, u16* __restrict__ oh, u16* __restrict__ ol)
{
    const int lane = threadIdx.x;
    const int qb = blockIdx.x, h = blockIdx.y, b = blockIdx.z;
    const int q = qb * 64 + lane;
    const float* qrow = qkv + (size_t)(b * SEQ + q) * 1536 + h * HDIM;
    float qr[64];
    #pragma unroll
    for (int d = 0; d < 64; d += 4) {
        float4 v = *(const float4*)(qrow + d);
        qr[d] = v.x * 0.125f; qr[d+1] = v.y * 0.125f; qr[d+2] = v.z * 0.125f; qr[d+3] = v.w * 0.125f;
    }
    float o[64];
    #pragma unroll
    for (int d = 0; d < 64; ++d) o[d] = 0.f;
    float l = 0.f;
    const int q0 = qb * 64;
    const int kstart = imaxi(0, q0 - (WIN - 1));
    const int kend = q0 + 63;
    for (int k = kstart; k <= kend; ++k) {
        const float* kr = qkv + (size_t)(b * SEQ + k) * 1536 + 512 + h * HDIM;  // wave-uniform
        float s0 = 0.f, s1 = 0.f, s2 = 0.f, s3 = 0.f;
        #pragma unroll
        for (int d = 0; d < 64; d += 4) {
            s0 += kr[d] * qr[d];     s1 += kr[d+1] * qr[d+1];
            s2 += kr[d+2] * qr[d+2]; s3 += kr[d+3] * qr[d+3];
        }
        float sc = (s0 + s1) + (s2 + s3);
        sc = (k <= q && k >= q - (WIN - 1)) ? sc : NEGV;
        float p = __expf(sc);        // exp(-1e9) underflows to exactly 0
        l += p;
        const float* vr = qkv + (size_t)(b * SEQ + k) * 1536 + 1024 + h * HDIM;
        #pragma unroll
        for (int d = 0; d < 64; ++d) o[d] += p * vr[d];
    }
    store_o_planes(o, 1.0f / l, oh, ol, (size_t)(b * SEQ + q) * DM + h * HDIM);
}

__global__ __launch_bounds__(64)
void attn_comp_k(const float* __restrict__ fq, const float* __restrict__ kc,
                 const float* __restrict__ vc, u16* __restrict__ oh, u16* __restrict__ ol)
{
    const int lane = threadIdx.x;
    const int qb = blockIdx.x, h = blockIdx.y, b = blockIdx.z;
    const int q = qb * 64 + lane;
    const float* qrow = fq + (size_t)(b * SEQ + q) * 2048 + h * HDIM;  // qc at col 0
    float qr[64];
    #pragma unroll
    for (int d = 0; d < 64; d += 4) {
        float4 v = *(const float4*)(qrow + d);
        qr[d] = v.x * 0.125f; qr[d+1] = v.y * 0.125f; qr[d+2] = v.z * 0.125f; qr[d+3] = v.w * 0.125f;
    }
    float o[64];
    #pragma unroll
    for (int d = 0; d < 64; ++d) o[d] = 0.f;
    float l = 0.f;
    for (int p = 0; p < NPOOLS; ++p) {
        const float* kr = kc + (size_t)(b * NPOOLS + p) * DM + h * HDIM;
        float s0 = 0.f, s1 = 0.f, s2 = 0.f, s3 = 0.f;
        #pragma unroll
        for (int d = 0; d < 64; d += 4) {
            s0 += kr[d] * qr[d];     s1 += kr[d+1] * qr[d+1];
            s2 += kr[d+2] * qr[d+2]; s3 += kr[d+3] * qr[d+3];
        }
        float sc = (s0 + s1) + (s2 + s3);
        sc = (q >= (p + 1) * RATIO) ? sc : NEGV;
        float pw = __expf(sc);
        l += pw;
        const float* vr = vc + (size_t)(b * NPOOLS + p) * DM + h * HDIM;
        #pragma unroll
        for (int d = 0; d < 64; ++d) o[d] += pw * vr[d];
    }
    if (l == 0.f) {  // all masked (q < 8): reference softmax is uniform over all pools
        for (int p = 0; p < NPOOLS; ++p) {
            const float* vr = vc + (size_t)(b * NPOOLS + p) * DM + h * HDIM;
            #pragma unroll
            for (int d = 0; d < 64; ++d) o[d] += vr[d];
        }
        l = (float)NPOOLS;
    }
    store_o_planes(o, 1.0f / l, oh, ol, (size_t)(b * SEQ + q) * DM + h * HDIM);
}

__global__ __launch_bounds__(64)
void attn_topk_k(const float* __restrict__ fq, const float* __restrict__ kt,
                 const float* __restrict__ vt, const int* __restrict__ tidx,
                 u16* __restrict__ oh, u16* __restrict__ ol)
{
    const int lane = threadIdx.x;
    const int qb = blockIdx.x, h = blockIdx.y, b = blockIdx.z;
    const int q = qb * 64 + lane;
    const float* qrow = fq + (size_t)(b * SEQ + q) * 2048 + 512 + h * HDIM;  // qt at col 512
    float qr[64];
    #pragma unroll
    for (int d = 0; d < 64; d += 4) {
        float4 v = *(const float4*)(qrow + d);
        qr[d] = v.x * 0.125f; qr[d+1] = v.y * 0.125f; qr[d+2] = v.z * 0.125f; qr[d+3] = v.w * 0.125f;
    }
    float o[64];
    #pragma unroll
    for (int d = 0; d < 64; ++d) o[d] = 0.f;
    float l = 0.f;
    const int* tix = tidx + b * TOPKN;
    for (int j = 0; j < TOPKN; ++j) {
        const float* kr = kt + (size_t)(b * TOPKN + j) * DM + h * HDIM;
        float s0 = 0.f, s1 = 0.f, s2 = 0.f, s3 = 0.f;
        #pragma unroll
        for (int d = 0; d < 64; d += 4) {
            s0 += kr[d] * qr[d];     s1 += kr[d+1] * qr[d+1];
            s2 += kr[d+2] * qr[d+2]; s3 += kr[d+3] * qr[d+3];
        }
        float sc = (s0 + s1) + (s2 + s3);
        sc = (q >= tix[j]) ? sc : NEGV;
        float pw = __expf(sc);
        l += pw;
        const float* vr = vt + (size_t)(b * TOPKN + j) * DM + h * HDIM;
        #pragma unroll
        for (int d = 0; d < 64; ++d) o[d] += pw * vr[d];
    }
    if (l == 0.f) {  // all masked: uniform over the 64 selected keys
        for (int j = 0; j < TOPKN; ++j) {
            const float* vr = vt + (size_t)(b * TOPKN + j) * DM + h * HDIM;
            #pragma unroll
            for (int d = 0; d < 64; ++d) o[d] += vr[d];
        }
        l = (float)TOPKN;
    }
    store_o_planes(o, 1.0f / l, oh, ol, (size_t)(b * SEQ + q) * DM + h * HDIM);
}

extern "C" void kernel_launch(void* const* d_in, const int* in_sizes, int n_in,
                              void* d_out, int out_size, void* d_ws, size_t ws_size,
                              hipStream_t stream)
{
    const float* x      = (const float*)d_in[0];
    const float* lqkv_W = (const float*)d_in[1];
    const float* lqkv_b = (const float*)d_in[2];
    const float* lout_W = (const float*)d_in[3];
    const float* lout_b = (const float*)d_in[4];
    const float* cq_W   = (const float*)d_in[5];
    const float* cq_b   = (const float*)d_in[6];
    const float* ck_W   = (const float*)d_in[7];
    const float* ck_b   = (const float*)d_in[8];
    const float* cv_W   = (const float*)d_in[9];
    const float* cv_b   = (const float*)d_in[10];
    const float* cout_W = (const float*)d_in[11];
    const float* cout_b = (const float*)d_in[12];
    const float* gc_W   = (const float*)d_in[13];
    const float* gc_b   = (const float*)d_in[14];
    const float* imp_W  = (const float*)d_in[15];
    const float* imp_b  = (const float*)d_in[16];
    const float* tq_W   = (const float*)d_in[17];
    const float* tq_b   = (const float*)d_in[18];
    const float* tk_W   = (const float*)d_in[19];
    const float* tk_b   = (const float*)d_in[20];
    const float* tv_W   = (const float*)d_in[21];
    const float* tv_b   = (const float*)d_in[22];
    const float* tout_W = (const float*)d_in[23];
    const float* tout_b = (const float*)d_in[24];
    const float* gt_W   = (const float*)d_in[25];
    const float* gt_b   = (const float*)d_in[26];
    float* out = (float*)d_out;

    // ---- workspace carve (bytes) ----
    char* wsb = (char*)d_ws;
    size_t off = 0;
    auto carve = [&](size_t bytes) { void* p = wsb + off; off += (bytes + 255) & ~(size_t)255; return p; };
    float* qkv   = (float*)carve(4096ull * 1536 * 4);   // local q|k|v
    float* fq    = (float*)carve(4096ull * 2048 * 4);   // qc|qt|gateC|gateT
    u16*   xh    = (u16*)  carve(4096ull * 512 * 2);
    u16*   xl    = (u16*)  carve(4096ull * 512 * 2);
    u16*   WqkvTh= (u16*)  carve(1536ull * 512 * 2);
    u16*   WqkvTl= (u16*)  carve(1536ull * 512 * 2);
    u16*   WcatTh= (u16*)  carve(2048ull * 512 * 2);
    u16*   WcatTl= (u16*)  carve(2048ull * 512 * 2);
    u16*   WLoTh = (u16*)  carve(512ull * 512 * 2);
    u16*   WLoTl = (u16*)  carve(512ull * 512 * 2);
    u16*   WCoTh = (u16*)  carve(512ull * 512 * 2);
    u16*   WCoTl = (u16*)  carve(512ull * 512 * 2);
    u16*   WToTh = (u16*)  carve(512ull * 512 * 2);
    u16*   WToTl = (u16*)  carve(512ull * 512 * 2);
    float* bcat  = (float*)carve(2048ull * 4);
    float* comp  = (float*)carve(384ull * 512 * 4);
    float* kc    = (float*)carve(384ull * 512 * 4);
    float* vc    = (float*)carve(384ull * 512 * 4);
    float* impb  = (float*)carve(4096ull * 4);
    int*   tidx  = (int*)  carve(128ull * 4);
    float* sel   = (float*)carve(128ull * 512 * 4);
    float* kt    = (float*)carve(128ull * 512 * 4);
    float* vt    = (float*)carve(128ull * 512 * 4);
    u16*   aLh   = (u16*)  carve(4096ull * 512 * 2);
    u16*   aLl   = (u16*)  carve(4096ull * 512 * 2);
    u16*   aCh   = (u16*)  carve(4096ull * 512 * 2);
    u16*   aCl   = (u16*)  carve(4096ull * 512 * 2);
    u16*   aTh   = (u16*)  carve(4096ull * 512 * 2);
    u16*   aTl   = (u16*)  carve(4096ull * 512 * 2);

    // ---- conversions (x + all big-GEMM weights) ----
    conv_act<<<1024, 256, 0, stream>>>(x, xh, xl, 4096 * 512 / 8);
    conv_wT<<<dim3(24, 8), 256, 0, stream>>>(lqkv_W, 1536, WqkvTh, WqkvTl, 0);
    conv_wT<<<dim3(8, 8), 256, 0, stream>>>(cq_W, 512, WcatTh, WcatTl, 0);
    conv_wT<<<dim3(8, 8), 256, 0, stream>>>(tq_W, 512, WcatTh, WcatTl, 512);
    conv_wT<<<dim3(8, 8), 256, 0, stream>>>(gc_W, 512, WcatTh, WcatTl, 1024);
    conv_wT<<<dim3(8, 8), 256, 0, stream>>>(gt_W, 512, WcatTh, WcatTl, 1536);
    conv_wT<<<dim3(8, 8), 256, 0, stream>>>(lout_W, 512, WLoTh, WLoTl, 0);
    conv_wT<<<dim3(8, 8), 256, 0, stream>>>(cout_W, 512, WCoTh, WCoTl, 0);
    conv_wT<<<dim3(8, 8), 256, 0, stream>>>(tout_W, 512, WToTh, WToTl, 0);
    bcat_fill<<<8, 256, 0, stream>>>(cq_b, tq_b, gc_b, gt_b, bcat);

    // ---- big projections via split-bf16 MFMA ----
    gemm_mfma<0><<<dim3(24, 32), 256, 0, stream>>>(xh, xl, WqkvTh, WqkvTl, lqkv_b, qkv, nullptr, 0, 1536);
    gemm_mfma<0><<<dim3(32, 32), 256, 0, stream>>>(xh, xl, WcatTh, WcatTl, bcat, fq, nullptr, 0, 2048);

    // ---- pooling + compressed K/V (small fp32 GEMMs) ----
    pool_x<<<384, 256, 0, stream>>>(x, comp);
    gemm_k512<4><<<dim3(8, 6), 256, 0, stream>>>(comp, ck_W, ck_b, kc, 384, 512);
    gemm_k512<4><<<dim3(8, 6), 256, 0, stream>>>(comp, cv_W, cv_b, vc, 384, 512);

    // ---- importance + top-k + gather + selected K/V ----
    gemv_imp<<<1024, 256, 0, stream>>>(x, imp_W, imp_b, impb);
    topk_sel<<<2, 64, 0, stream>>>(impb, tidx);
    gather_sel<<<128, 256, 0, stream>>>(x, tidx, sel);
    gemm_k512<4><<<dim3(8, 2), 256, 0, stream>>>(sel, tk_W, tk_b, kt, 128, 512);   // (8,2): M=128 needs 2 m-blocks
    gemm_k512<4><<<dim3(8, 2), 256, 0, stream>>>(sel, tv_W, tv_b, vt, 128, 512);

    // ---- three attention branches (emit hi/lo bf16 planes) ----
    attn_local_k<<<dim3(32, 8, 2), 64, 0, stream>>>(qkv, aLh, aLl);
    attn_comp_k<<<dim3(32, 8, 2), 64, 0, stream>>>(fq, kc, vc, aCh, aCl);
    attn_topk_k<<<dim3(32, 8, 2), 64, 0, stream>>>(fq, kt, vt, tidx, aTh, aTl);

    // ---- output projections: out = projL + sig(gC)*projC + sig(gT)*projT ----
    gemm_mfma<0><<<dim3(8, 32), 256, 0, stream>>>(aLh, aLl, WLoTh, WLoTl, lout_b, out, nullptr, 0, 512);
    gemm_mfma<1><<<dim3(8, 32), 256, 0, stream>>>(aCh, aCl, WCoTh, WCoTl, cout_b, out, fq + 1024, 2048, 512);
    gemm_mfma<1><<<dim3(8, 32), 256, 0, stream>>>(aTh, aTl, WToTh, WToTl, tout_b, out, fq + 1536, 2048, 512);
}

// Round 3
// 915.235 us; speedup vs baseline: 1.6869x; 1.6869x over previous
//
#include <hip/hip_runtime.h>
#include <cstdint>
#include <cstddef>

#define HNUM 8
#define HDIM 64
#define WIN 512
#define RATIO 8
#define TOPKN 64
#define BATCH 2
#define SEQ 2048
#define DM 512
#define NPOOLS 192
#define NEGV (-1000000000.0f)

typedef unsigned short u16;
typedef __attribute__((ext_vector_type(8))) short bf16x8;
typedef __attribute__((ext_vector_type(4))) float f32x4;

static __device__ __forceinline__ int imaxi(int a, int b){ return a > b ? a : b; }

// bf16 round-to-nearest-even via bit ops (inputs finite)
static __device__ __forceinline__ u16 f2bf(float v) {
    union { float f; uint32_t u; } c; c.f = v;
    uint32_t r = c.u + 0x7fffu + ((c.u >> 16) & 1u);
    return (u16)(r >> 16);
}
static __device__ __forceinline__ float bf2f(u16 u) {
    union { uint32_t u; float f; } c; c.u = ((uint32_t)u) << 16;
    return c.f;
}

// ---------------- fp32 -> (hi, lo) bf16 planes, elementwise ----------------
__global__ __launch_bounds__(256)
void conv_act(const float* __restrict__ in, u16* __restrict__ h, u16* __restrict__ l, int n8)
{
    int i = blockIdx.x * 256 + threadIdx.x;
    if (i >= n8) return;
    const float4* p = (const float4*)(in + (size_t)i * 8);
    float4 a = p[0], b = p[1];
    float v[8] = {a.x, a.y, a.z, a.w, b.x, b.y, b.z, b.w};
    u16 hs[8], ls[8];
    #pragma unroll
    for (int j = 0; j < 8; ++j) {
        hs[j] = f2bf(v[j]);
        ls[j] = f2bf(v[j] - bf2f(hs[j]));
    }
    *(uint4*)(h + (size_t)i * 8) = *(uint4*)hs;
    *(uint4*)(l + (size_t)i * 8) = *(uint4*)ls;
}

// ------------- weight transpose-convert: W[512][N] -> WT planes [N][512] -------------
__global__ __launch_bounds__(256)
void conv_wT(const float* __restrict__ W, int N,
             u16* __restrict__ WTh, u16* __restrict__ WTl, int dstRowOff)
{
    __shared__ float t[64][65];
    const int n0 = blockIdx.x * 64, k0 = blockIdx.y * 64;
    const int tid = threadIdx.x;
    const int tk = tid >> 4, tn = (tid & 15) * 4;
    #pragma unroll
    for (int r = 0; r < 4; ++r) {
        int k = tk + r * 16;
        float4 v = *(const float4*)(W + (size_t)(k0 + k) * N + n0 + tn);
        t[k][tn + 0] = v.x; t[k][tn + 1] = v.y; t[k][tn + 2] = v.z; t[k][tn + 3] = v.w;
    }
    __syncthreads();
    const int nl = tid >> 2, s = tid & 3;
    u16 hs[16], ls[16];
    #pragma unroll
    for (int j = 0; j < 16; ++j) {
        float v = t[s * 16 + j][nl];
        hs[j] = f2bf(v);
        ls[j] = f2bf(v - bf2f(hs[j]));
    }
    size_t base = (size_t)(dstRowOff + n0 + nl) * 512 + k0 + s * 16;
    *(uint4*)(WTh + base)     = ((uint4*)hs)[0];
    *(uint4*)(WTh + base + 8) = ((uint4*)hs)[1];
    *(uint4*)(WTl + base)     = ((uint4*)ls)[0];
    *(uint4*)(WTl + base + 8) = ((uint4*)ls)[1];
}

// ---------------- bias concat for fused q/gate GEMM ----------------
__global__ void bcat_fill(const float* __restrict__ b0, const float* __restrict__ b1,
                          const float* __restrict__ b2, const float* __restrict__ b3,
                          float* __restrict__ bcat)
{
    int i = blockIdx.x * 256 + threadIdx.x;
    if (i < 512) bcat[i] = b0[i];
    else if (i < 1024) bcat[i] = b1[i - 512];
    else if (i < 1536) bcat[i] = b2[i - 1024];
    else if (i < 2048) bcat[i] = b3[i - 1536];
}

// ---------------- split-bf16 MFMA GEMM: M=4096, K=512 ----------------
template<int MODE>
__global__ __launch_bounds__(256)
void gemm_mfma(const u16* __restrict__ Ah, const u16* __restrict__ Al,
               const u16* __restrict__ BTh, const u16* __restrict__ BTl,
               const float* __restrict__ bias, float* __restrict__ C,
               const float* __restrict__ G, int gstride, int N)
{
    __shared__ __align__(16) u16 AsH[128 * 40], AsL[128 * 40], BsH[64 * 40], BsL[64 * 40];
    const int tid = threadIdx.x;
    const int m0 = blockIdx.y * 128, n0 = blockIdx.x * 64;
    const int wid = tid >> 6, lane = tid & 63;
    const int wm = (wid >> 1) * 64, wn = (wid & 1) * 32;
    const int lr = lane & 15, lg = lane >> 4;

    f32x4 acc[4][2];
    #pragma unroll
    for (int i = 0; i < 4; ++i)
        #pragma unroll
        for (int j = 0; j < 2; ++j) acc[i][j] = (f32x4){0.f, 0.f, 0.f, 0.f};

    const int r0 = tid >> 2, s = tid & 3;

    for (int k0 = 0; k0 < 512; k0 += 32) {
        __syncthreads();
        size_t ga = (size_t)(m0 + r0) * 512 + k0 + s * 8;
        *(uint4*)&AsH[r0 * 40 + s * 8] = *(const uint4*)(Ah + ga);
        *(uint4*)&AsL[r0 * 40 + s * 8] = *(const uint4*)(Al + ga);
        size_t gb = (size_t)(m0 + r0 + 64) * 512 + k0 + s * 8;
        *(uint4*)&AsH[(r0 + 64) * 40 + s * 8] = *(const uint4*)(Ah + gb);
        *(uint4*)&AsL[(r0 + 64) * 40 + s * 8] = *(const uint4*)(Al + gb);
        size_t gc = (size_t)(n0 + r0) * 512 + k0 + s * 8;
        *(uint4*)&BsH[r0 * 40 + s * 8] = *(const uint4*)(BTh + gc);
        *(uint4*)&BsL[r0 * 40 + s * 8] = *(const uint4*)(BTl + gc);
        __syncthreads();

        bf16x8 ah[4], al[4], bh[2], bl[2];
        #pragma unroll
        for (int i = 0; i < 4; ++i) {
            int row = wm + i * 16 + lr;
            ah[i] = *(const bf16x8*)&AsH[row * 40 + lg * 8];
            al[i] = *(const bf16x8*)&AsL[row * 40 + lg * 8];
        }
        #pragma unroll
        for (int j = 0; j < 2; ++j) {
            int row = wn + j * 16 + lr;
            bh[j] = *(const bf16x8*)&BsH[row * 40 + lg * 8];
            bl[j] = *(const bf16x8*)&BsL[row * 40 + lg * 8];
        }
        #pragma unroll
        for (int i = 0; i < 4; ++i)
            #pragma unroll
            for (int j = 0; j < 2; ++j) {
                acc[i][j] = __builtin_amdgcn_mfma_f32_16x16x32_bf16(ah[i], bh[j], acc[i][j], 0, 0, 0);
                acc[i][j] = __builtin_amdgcn_mfma_f32_16x16x32_bf16(ah[i], bl[j], acc[i][j], 0, 0, 0);
                acc[i][j] = __builtin_amdgcn_mfma_f32_16x16x32_bf16(al[i], bh[j], acc[i][j], 0, 0, 0);
            }
    }

    #pragma unroll
    for (int i = 0; i < 4; ++i)
        #pragma unroll
        for (int j = 0; j < 2; ++j) {
            int col = n0 + wn + j * 16 + lr;
            float bs = bias[col];
            #pragma unroll
            for (int r = 0; r < 4; ++r) {
                int row = m0 + wm + i * 16 + lg * 4 + r;
                float v = acc[i][j][r] + bs;
                size_t idx = (size_t)row * N + col;
                if (MODE == 0) C[idx] = v;
                else {
                    float g = G[(size_t)row * gstride + col];
                    C[idx] += v / (1.0f + __expf(-g));
                }
            }
        }
}

// ---------------- fp32 vector GEMM for the small matrices ----------------
template<int TM>
__global__ __launch_bounds__(256)
void gemm_k512(const float* __restrict__ A, const float* __restrict__ W,
               const float* __restrict__ bias, float* __restrict__ C,
               int M, int N)
{
    constexpr int BM = TM * 16;
    constexpr int BK = 32;
    __shared__ float As[BK][BM + 4];
    __shared__ float Bs[BK][64 + 4];
    const int tid = threadIdx.x;
    const int m0 = blockIdx.y * BM;
    const int n0 = blockIdx.x * 64;
    const int tm = tid >> 4, tn = tid & 15;
    float acc[TM][4];
    #pragma unroll
    for (int i = 0; i < TM; ++i)
        #pragma unroll
        for (int j = 0; j < 4; ++j) acc[i][j] = 0.f;

    for (int k0 = 0; k0 < 512; k0 += BK) {
        #pragma unroll
        for (int f = tid; f < BM * 8; f += 256) {
            int row = f >> 3, c4 = f & 7;
            float4 av = *(const float4*)(A + (size_t)(m0 + row) * 512 + k0 + c4 * 4);
            As[c4 * 4 + 0][row] = av.x;
            As[c4 * 4 + 1][row] = av.y;
            As[c4 * 4 + 2][row] = av.z;
            As[c4 * 4 + 3][row] = av.w;
        }
        #pragma unroll
        for (int f = tid; f < 512; f += 256) {
            int row = f >> 4, c4 = f & 15;
            *(float4*)(&Bs[row][c4 * 4]) = *(const float4*)(W + (size_t)(k0 + row) * N + n0 + c4 * 4);
        }
        __syncthreads();
        #pragma unroll
        for (int kk = 0; kk < BK; ++kk) {
            float a[TM], bb[4];
            #pragma unroll
            for (int i4 = 0; i4 < TM / 4; ++i4)
                *(float4*)(&a[i4 * 4]) = *(const float4*)(&As[kk][tm * TM + i4 * 4]);
            *(float4*)(bb) = *(const float4*)(&Bs[kk][tn * 4]);
            #pragma unroll
            for (int i = 0; i < TM; ++i)
                #pragma unroll
                for (int j = 0; j < 4; ++j)
                    acc[i][j] += a[i] * bb[j];
        }
        __syncthreads();
    }
    #pragma unroll
    for (int i = 0; i < TM; ++i) {
        int m = m0 + tm * TM + i;
        #pragma unroll
        for (int j = 0; j < 4; ++j) {
            int n = n0 + tn * 4 + j;
            C[(size_t)m * N + n] = acc[i][j] + bias[n];
        }
    }
}

// ---------------- mean-pool x over groups of 8 tokens (first 1536) ----------------
__global__ void pool_x(const float* __restrict__ x, float* __restrict__ comp)
{
    int row = blockIdx.x;
    int b = row / NPOOLS, p = row % NPOOLS;
    const float* src = x + ((size_t)b * SEQ + (size_t)p * RATIO) * DM;
    float* dst = comp + (size_t)row * DM;
    for (int d = threadIdx.x; d < DM; d += 256) {
        float sv = 0.f;
        #pragma unroll
        for (int r = 0; r < RATIO; ++r) sv += src[(size_t)r * DM + d];
        dst[d] = sv * 0.125f;
    }
}

// ---------------- importance GEMV ----------------
__global__ __launch_bounds__(256)
void gemv_imp(const float* __restrict__ x, const float* __restrict__ w,
              const float* __restrict__ bsc, float* __restrict__ imp)
{
    int row = blockIdx.x * 4 + (threadIdx.x >> 6);
    int lane = threadIdx.x & 63;
    const float* xr = x + (size_t)row * DM;
    float sv = 0.f;
    #pragma unroll
    for (int i = 0; i < 8; ++i) sv += xr[lane + i * 64] * w[lane + i * 64];
    #pragma unroll
    for (int off = 32; off; off >>= 1) sv += __shfl_xor(sv, off);
    if (lane == 0) imp[row] = sv + bsc[0];
}

// ---------------- top-64 per batch ----------------
__global__ __launch_bounds__(64)
void topk_sel(const float* __restrict__ imp, int* __restrict__ tidx)
{
    __shared__ float vals[SEQ];
    int b = blockIdx.x;
    int lane = threadIdx.x;
    for (int i = lane; i < SEQ; i += 64) vals[i] = imp[(size_t)b * SEQ + i];
    __syncthreads();
    for (int r = 0; r < TOPKN; ++r) {
        float bv = -1e30f; int bi = 0x7fffffff;
        for (int i = lane; i < SEQ; i += 64) {
            float v = vals[i];
            if (v > bv) { bv = v; bi = i; }
        }
        #pragma unroll
        for (int off = 32; off; off >>= 1) {
            float ov = __shfl_xor(bv, off);
            int oi = __shfl_xor(bi, off);
            if (ov > bv || (ov == bv && oi < bi)) { bv = ov; bi = oi; }
        }
        if (lane == 0) {
            tidx[b * TOPKN + r] = bi;
            vals[bi] = -1e30f;
        }
        __syncthreads();
    }
}

// ---------------- gather selected rows of x ----------------
__global__ void gather_sel(const float* __restrict__ x, const int* __restrict__ tidx,
                           float* __restrict__ sel)
{
    int r = blockIdx.x;
    int b = r >> 6;
    int t = tidx[r];
    const float* src = x + ((size_t)b * SEQ + t) * DM;
    float* dst = sel + (size_t)r * DM;
    for (int j = threadIdx.x; j < DM; j += 256) dst[j] = src[j];
}

// =====================================================================
// Attention v2: 256-thread blocks, 4 waves; each wave = 8 queries x 8 lanes;
// lane (g,e) owns dims [e*8, e*8+8) of query (waveQ0+g). Per-thread state:
// qr[8] + o[8] -> register-resident (v1 spilled 128 floats to scratch).
// Dot-product reduced across the 8-lane group via 3 shfl_xor.
// =====================================================================
static __device__ __forceinline__ void attn_store8(const float* o, float inv,
                                                   u16* oh, u16* ol, size_t base)
{
    u16 hs[8], ls[8];
    #pragma unroll
    for (int j = 0; j < 8; ++j) {
        float v = o[j] * inv;
        hs[j] = f2bf(v);
        ls[j] = f2bf(v - bf2f(hs[j]));
    }
    *(uint4*)(oh + base) = *(uint4*)hs;
    *(uint4*)(ol + base) = *(uint4*)ls;
}

__global__ __launch_bounds__(256)
void attn_local2(const float* __restrict__ qkv, u16* __restrict__ oh, u16* __restrict__ ol)
{
    const int tid = threadIdx.x;
    const int w = tid >> 6, lane = tid & 63;
    const int g = lane >> 3, e = lane & 7;
    const int h = blockIdx.y, b = blockIdx.z;
    const int qw0 = blockIdx.x * 32 + w * 8;     // wave's first query
    const int qq = qw0 + g;                      // this lane's query
    const float* qrow = qkv + (size_t)(b * SEQ + qq) * 1536 + h * HDIM + e * 8;
    float4 qa = *(const float4*)qrow, qb = *(const float4*)(qrow + 4);
    float qr[8] = {qa.x * 0.125f, qa.y * 0.125f, qa.z * 0.125f, qa.w * 0.125f,
                   qb.x * 0.125f, qb.y * 0.125f, qb.z * 0.125f, qb.w * 0.125f};
    float o[8] = {0.f, 0.f, 0.f, 0.f, 0.f, 0.f, 0.f, 0.f};
    float l = 0.f;
    const int kstart = imaxi(0, qw0 - (WIN - 1));
    const int kend = qw0 + 7;
    const float* kp = qkv + (size_t)(b * SEQ + kstart) * 1536 + 512 + h * HDIM + e * 8;
    const float* vp = kp + 512;
    for (int k = kstart; k <= kend; ++k) {
        float4 ka = *(const float4*)kp, kb = *(const float4*)(kp + 4);
        float s = ka.x * qr[0] + ka.y * qr[1] + ka.z * qr[2] + ka.w * qr[3]
                + kb.x * qr[4] + kb.y * qr[5] + kb.z * qr[6] + kb.w * qr[7];
        s += __shfl_xor(s, 1); s += __shfl_xor(s, 2); s += __shfl_xor(s, 4);
        s = (k <= qq && k > qq - WIN) ? s : NEGV;
        float pw = __expf(s);                    // exp(-1e9) -> exactly 0
        l += pw;
        float4 va = *(const float4*)vp, vb = *(const float4*)(vp + 4);
        o[0] += pw * va.x; o[1] += pw * va.y; o[2] += pw * va.z; o[3] += pw * va.w;
        o[4] += pw * vb.x; o[5] += pw * vb.y; o[6] += pw * vb.z; o[7] += pw * vb.w;
        kp += 1536; vp += 1536;
    }
    attn_store8(o, 1.0f / l, oh, ol, (size_t)(b * SEQ + qq) * DM + h * HDIM + e * 8);
}

__global__ __launch_bounds__(256)
void attn_comp2(const float* __restrict__ fq, const float* __restrict__ kc,
                const float* __restrict__ vc, u16* __restrict__ oh, u16* __restrict__ ol)
{
    const int tid = threadIdx.x;
    const int w = tid >> 6, lane = tid & 63;
    const int g = lane >> 3, e = lane & 7;
    const int h = blockIdx.y, b = blockIdx.z;
    const int qq = blockIdx.x * 32 + w * 8 + g;
    const float* qrow = fq + (size_t)(b * SEQ + qq) * 2048 + h * HDIM + e * 8;   // qc @ col 0
    float4 qa = *(const float4*)qrow, qb = *(const float4*)(qrow + 4);
    float qr[8] = {qa.x * 0.125f, qa.y * 0.125f, qa.z * 0.125f, qa.w * 0.125f,
                   qb.x * 0.125f, qb.y * 0.125f, qb.z * 0.125f, qb.w * 0.125f};
    float o[8] = {0.f, 0.f, 0.f, 0.f, 0.f, 0.f, 0.f, 0.f};
    float l = 0.f;
    const float* kp = kc + (size_t)(b * NPOOLS) * DM + h * HDIM + e * 8;
    const float* vp = vc + (size_t)(b * NPOOLS) * DM + h * HDIM + e * 8;
    for (int p = 0; p < NPOOLS; ++p) {
        float4 ka = *(const float4*)(kp + (size_t)p * DM), kb = *(const float4*)(kp + (size_t)p * DM + 4);
        float s = ka.x * qr[0] + ka.y * qr[1] + ka.z * qr[2] + ka.w * qr[3]
                + kb.x * qr[4] + kb.y * qr[5] + kb.z * qr[6] + kb.w * qr[7];
        s += __shfl_xor(s, 1); s += __shfl_xor(s, 2); s += __shfl_xor(s, 4);
        s = (qq >= (p + 1) * RATIO) ? s : NEGV;
        float pw = __expf(s);
        l += pw;
        float4 va = *(const float4*)(vp + (size_t)p * DM), vb = *(const float4*)(vp + (size_t)p * DM + 4);
        o[0] += pw * va.x; o[1] += pw * va.y; o[2] += pw * va.z; o[3] += pw * va.w;
        o[4] += pw * vb.x; o[5] += pw * vb.y; o[6] += pw * vb.z; o[7] += pw * vb.w;
    }
    if (l == 0.f) {   // q < 8: all masked -> reference softmax is uniform over pools
        for (int p = 0; p < NPOOLS; ++p) {
            float4 va = *(const float4*)(vp + (size_t)p * DM), vb = *(const float4*)(vp + (size_t)p * DM + 4);
            o[0] += va.x; o[1] += va.y; o[2] += va.z; o[3] += va.w;
            o[4] += vb.x; o[5] += vb.y; o[6] += vb.z; o[7] += vb.w;
        }
        l = (float)NPOOLS;
    }
    attn_store8(o, 1.0f / l, oh, ol, (size_t)(b * SEQ + qq) * DM + h * HDIM + e * 8);
}

__global__ __launch_bounds__(256)
void attn_topk2(const float* __restrict__ fq, const float* __restrict__ kt,
                const float* __restrict__ vt, const int* __restrict__ tidx,
                u16* __restrict__ oh, u16* __restrict__ ol)
{
    const int tid = threadIdx.x;
    const int w = tid >> 6, lane = tid & 63;
    const int g = lane >> 3, e = lane & 7;
    const int h = blockIdx.y, b = blockIdx.z;
    const int qq = blockIdx.x * 32 + w * 8 + g;
    const float* qrow = fq + (size_t)(b * SEQ + qq) * 2048 + 512 + h * HDIM + e * 8;  // qt @ col 512
    float4 qa = *(const float4*)qrow, qb = *(const float4*)(qrow + 4);
    float qr[8] = {qa.x * 0.125f, qa.y * 0.125f, qa.z * 0.125f, qa.w * 0.125f,
                   qb.x * 0.125f, qb.y * 0.125f, qb.z * 0.125f, qb.w * 0.125f};
    float o[8] = {0.f, 0.f, 0.f, 0.f, 0.f, 0.f, 0.f, 0.f};
    float l = 0.f;
    const int* tix = tidx + b * TOPKN;
    const float* kp = kt + (size_t)(b * TOPKN) * DM + h * HDIM + e * 8;
    const float* vp = vt + (size_t)(b * TOPKN) * DM + h * HDIM + e * 8;
    for (int j = 0; j < TOPKN; ++j) {
        float4 ka = *(const float4*)(kp + (size_t)j * DM), kb = *(const float4*)(kp + (size_t)j * DM + 4);
        float s = ka.x * qr[0] + ka.y * qr[1] + ka.z * qr[2] + ka.w * qr[3]
                + kb.x * qr[4] + kb.y * qr[5] + kb.z * qr[6] + kb.w * qr[7];
        s += __shfl_xor(s, 1); s += __shfl_xor(s, 2); s += __shfl_xor(s, 4);
        s = (qq >= tix[j]) ? s : NEGV;
        float pw = __expf(s);
        l += pw;
        float4 va = *(const float4*)(vp + (size_t)j * DM), vb = *(const float4*)(vp + (size_t)j * DM + 4);
        o[0] += pw * va.x; o[1] += pw * va.y; o[2] += pw * va.z; o[3] += pw * va.w;
        o[4] += pw * vb.x; o[5] += pw * vb.y; o[6] += pw * vb.z; o[7] += pw * vb.w;
    }
    if (l == 0.f) {   // q < min(tidx): uniform over the 64 selected keys
        for (int j = 0; j < TOPKN; ++j) {
            float4 va = *(const float4*)(vp + (size_t)j * DM), vb = *(const float4*)(vp + (size_t)j * DM + 4);
            o[0] += va.x; o[1] += va.y; o[2] += va.z; o[3] += va.w;
            o[4] += vb.x; o[5] += vb.y; o[6] += vb.z; o[7] += vb.w;
        }
        l = (float)TOPKN;
    }
    attn_store8(o, 1.0f / l, oh, ol, (size_t)(b * SEQ + qq) * DM + h * HDIM + e * 8);
}

extern "C" void kernel_launch(void* const* d_in, const int* in_sizes, int n_in,
                              void* d_out, int out_size, void* d_ws, size_t ws_size,
                              hipStream_t stream)
{
    const float* x      = (const float*)d_in[0];
    const float* lqkv_W = (const float*)d_in[1];
    const float* lqkv_b = (const float*)d_in[2];
    const float* lout_W = (const float*)d_in[3];
    const float* lout_b = (const float*)d_in[4];
    const float* cq_W   = (const float*)d_in[5];
    const float* cq_b   = (const float*)d_in[6];
    const float* ck_W   = (const float*)d_in[7];
    const float* ck_b   = (const float*)d_in[8];
    const float* cv_W   = (const float*)d_in[9];
    const float* cv_b   = (const float*)d_in[10];
    const float* cout_W = (const float*)d_in[11];
    const float* cout_b = (const float*)d_in[12];
    const float* gc_W   = (const float*)d_in[13];
    const float* gc_b   = (const float*)d_in[14];
    const float* imp_W  = (const float*)d_in[15];
    const float* imp_b  = (const float*)d_in[16];
    const float* tq_W   = (const float*)d_in[17];
    const float* tq_b   = (const float*)d_in[18];
    const float* tk_W   = (const float*)d_in[19];
    const float* tk_b   = (const float*)d_in[20];
    const float* tv_W   = (const float*)d_in[21];
    const float* tv_b   = (const float*)d_in[22];
    const float* tout_W = (const float*)d_in[23];
    const float* tout_b = (const float*)d_in[24];
    const float* gt_W   = (const float*)d_in[25];
    const float* gt_b   = (const float*)d_in[26];
    float* out = (float*)d_out;

    char* wsb = (char*)d_ws;
    size_t off = 0;
    auto carve = [&](size_t bytes) { void* p = wsb + off; off += (bytes + 255) & ~(size_t)255; return p; };
    float* qkv   = (float*)carve(4096ull * 1536 * 4);
    float* fq    = (float*)carve(4096ull * 2048 * 4);
    u16*   xh    = (u16*)  carve(4096ull * 512 * 2);
    u16*   xl    = (u16*)  carve(4096ull * 512 * 2);
    u16*   WqkvTh= (u16*)  carve(1536ull * 512 * 2);
    u16*   WqkvTl= (u16*)  carve(1536ull * 512 * 2);
    u16*   WcatTh= (u16*)  carve(2048ull * 512 * 2);
    u16*   WcatTl= (u16*)  carve(2048ull * 512 * 2);
    u16*   WLoTh = (u16*)  carve(512ull * 512 * 2);
    u16*   WLoTl = (u16*)  carve(512ull * 512 * 2);
    u16*   WCoTh = (u16*)  carve(512ull * 512 * 2);
    u16*   WCoTl = (u16*)  carve(512ull * 512 * 2);
    u16*   WToTh = (u16*)  carve(512ull * 512 * 2);
    u16*   WToTl = (u16*)  carve(512ull * 512 * 2);
    float* bcat  = (float*)carve(2048ull * 4);
    float* comp  = (float*)carve(384ull * 512 * 4);
    float* kc    = (float*)carve(384ull * 512 * 4);
    float* vc    = (float*)carve(384ull * 512 * 4);
    float* impb  = (float*)carve(4096ull * 4);
    int*   tidx  = (int*)  carve(128ull * 4);
    float* sel   = (float*)carve(128ull * 512 * 4);
    float* kt    = (float*)carve(128ull * 512 * 4);
    float* vt    = (float*)carve(128ull * 512 * 4);
    u16*   aLh   = (u16*)  carve(4096ull * 512 * 2);
    u16*   aLl   = (u16*)  carve(4096ull * 512 * 2);
    u16*   aCh   = (u16*)  carve(4096ull * 512 * 2);
    u16*   aCl   = (u16*)  carve(4096ull * 512 * 2);
    u16*   aTh   = (u16*)  carve(4096ull * 512 * 2);
    u16*   aTl   = (u16*)  carve(4096ull * 512 * 2);

    // ---- conversions ----
    conv_act<<<1024, 256, 0, stream>>>(x, xh, xl, 4096 * 512 / 8);
    conv_wT<<<dim3(24, 8), 256, 0, stream>>>(lqkv_W, 1536, WqkvTh, WqkvTl, 0);
    conv_wT<<<dim3(8, 8), 256, 0, stream>>>(cq_W, 512, WcatTh, WcatTl, 0);
    conv_wT<<<dim3(8, 8), 256, 0, stream>>>(tq_W, 512, WcatTh, WcatTl, 512);
    conv_wT<<<dim3(8, 8), 256, 0, stream>>>(gc_W, 512, WcatTh, WcatTl, 1024);
    conv_wT<<<dim3(8, 8), 256, 0, stream>>>(gt_W, 512, WcatTh, WcatTl, 1536);
    conv_wT<<<dim3(8, 8), 256, 0, stream>>>(lout_W, 512, WLoTh, WLoTl, 0);
    conv_wT<<<dim3(8, 8), 256, 0, stream>>>(cout_W, 512, WCoTh, WCoTl, 0);
    conv_wT<<<dim3(8, 8), 256, 0, stream>>>(tout_W, 512, WToTh, WToTl, 0);
    bcat_fill<<<8, 256, 0, stream>>>(cq_b, tq_b, gc_b, gt_b, bcat);

    // ---- big projections via split-bf16 MFMA ----
    gemm_mfma<0><<<dim3(24, 32), 256, 0, stream>>>(xh, xl, WqkvTh, WqkvTl, lqkv_b, qkv, nullptr, 0, 1536);
    gemm_mfma<0><<<dim3(32, 32), 256, 0, stream>>>(xh, xl, WcatTh, WcatTl, bcat, fq, nullptr, 0, 2048);

    // ---- pooling + compressed K/V ----
    pool_x<<<384, 256, 0, stream>>>(x, comp);
    gemm_k512<4><<<dim3(8, 6), 256, 0, stream>>>(comp, ck_W, ck_b, kc, 384, 512);
    gemm_k512<4><<<dim3(8, 6), 256, 0, stream>>>(comp, cv_W, cv_b, vc, 384, 512);

    // ---- importance + top-k + gather + selected K/V ----
    gemv_imp<<<1024, 256, 0, stream>>>(x, imp_W, imp_b, impb);
    topk_sel<<<2, 64, 0, stream>>>(impb, tidx);
    gather_sel<<<128, 256, 0, stream>>>(x, tidx, sel);
    gemm_k512<4><<<dim3(8, 2), 256, 0, stream>>>(sel, tk_W, tk_b, kt, 128, 512);
    gemm_k512<4><<<dim3(8, 2), 256, 0, stream>>>(sel, tv_W, tv_b, vt, 128, 512);

    // ---- attention v2 (register-resident; 16 waves/CU) ----
    attn_local2<<<dim3(64, 8, 2), 256, 0, stream>>>(qkv, aLh, aLl);
    attn_comp2<<<dim3(64, 8, 2), 256, 0, stream>>>(fq, kc, vc, aCh, aCl);
    attn_topk2<<<dim3(64, 8, 2), 256, 0, stream>>>(fq, kt, vt, tidx, aTh, aTl);

    // ---- output projections: out = projL + sig(gC)*projC + sig(gT)*projT ----
    gemm_mfma<0><<<dim3(8, 32), 256, 0, stream>>>(aLh, aLl, WLoTh, WLoTl, lout_b, out, nullptr, 0, 512);
    gemm_mfma<1><<<dim3(8, 32), 256, 0, stream>>>(aCh, aCl, WCoTh, WCoTl, cout_b, out, fq + 1024, 2048, 512);
    gemm_mfma<1><<<dim3(8, 32), 256, 0, stream>>>(aTh, aTl, WToTh, WToTl, tout_b, out, fq + 1536, 2048, 512);
}

// Round 4
// 600.356 us; speedup vs baseline: 2.5717x; 1.5245x over previous
//
#include <hip/hip_runtime.h>
#include <cstdint>
#include <cstddef>

#define HNUM 8
#define HDIM 64
#define WIN 512
#define RATIO 8
#define TOPKN 64
#define BATCH 2
#define SEQ 2048
#define DM 512
#define NPOOLS 192
#define NEGV (-1000000000.0f)

typedef unsigned short u16;
typedef __attribute__((ext_vector_type(8))) short bf16x8;
typedef __attribute__((ext_vector_type(4))) float f32x4;

static __device__ __forceinline__ int imaxi(int a, int b){ return a > b ? a : b; }
static __device__ __forceinline__ int imini(int a, int b){ return a < b ? a : b; }

// bf16 round-to-nearest-even via bit ops (inputs finite)
static __device__ __forceinline__ u16 f2bf(float v) {
    union { float f; uint32_t u; } c; c.f = v;
    uint32_t r = c.u + 0x7fffu + ((c.u >> 16) & 1u);
    return (u16)(r >> 16);
}
static __device__ __forceinline__ float bf2f(u16 u) {
    union { uint32_t u; float f; } c; c.u = ((uint32_t)u) << 16;
    return c.f;
}

// ---------------- fp32 -> (hi, lo) bf16 planes, elementwise ----------------
__global__ __launch_bounds__(256)
void conv_act(const float* __restrict__ in, u16* __restrict__ h, u16* __restrict__ l, int n8)
{
    int i = blockIdx.x * 256 + threadIdx.x;
    if (i >= n8) return;
    const float4* p = (const float4*)(in + (size_t)i * 8);
    float4 a = p[0], b = p[1];
    float v[8] = {a.x, a.y, a.z, a.w, b.x, b.y, b.z, b.w};
    u16 hs[8], ls[8];
    #pragma unroll
    for (int j = 0; j < 8; ++j) {
        hs[j] = f2bf(v[j]);
        ls[j] = f2bf(v[j] - bf2f(hs[j]));
    }
    *(uint4*)(h + (size_t)i * 8) = *(uint4*)hs;
    *(uint4*)(l + (size_t)i * 8) = *(uint4*)ls;
}

// ------------- weight transpose-convert: W[512][N] -> WT planes [N][512] -------------
__global__ __launch_bounds__(256)
void conv_wT(const float* __restrict__ W, int N,
             u16* __restrict__ WTh, u16* __restrict__ WTl, int dstRowOff)
{
    __shared__ float t[64][65];
    const int n0 = blockIdx.x * 64, k0 = blockIdx.y * 64;
    const int tid = threadIdx.x;
    const int tk = tid >> 4, tn = (tid & 15) * 4;
    #pragma unroll
    for (int r = 0; r < 4; ++r) {
        int k = tk + r * 16;
        float4 v = *(const float4*)(W + (size_t)(k0 + k) * N + n0 + tn);
        t[k][tn + 0] = v.x; t[k][tn + 1] = v.y; t[k][tn + 2] = v.z; t[k][tn + 3] = v.w;
    }
    __syncthreads();
    const int nl = tid >> 2, s = tid & 3;
    u16 hs[16], ls[16];
    #pragma unroll
    for (int j = 0; j < 16; ++j) {
        float v = t[s * 16 + j][nl];
        hs[j] = f2bf(v);
        ls[j] = f2bf(v - bf2f(hs[j]));
    }
    size_t base = (size_t)(dstRowOff + n0 + nl) * 512 + k0 + s * 16;
    *(uint4*)(WTh + base)     = ((uint4*)hs)[0];
    *(uint4*)(WTh + base + 8) = ((uint4*)hs)[1];
    *(uint4*)(WTl + base)     = ((uint4*)ls)[0];
    *(uint4*)(WTl + base + 8) = ((uint4*)ls)[1];
}

// ---------------- bias concat for fused q/gate GEMM ----------------
__global__ void bcat_fill(const float* __restrict__ b0, const float* __restrict__ b1,
                          const float* __restrict__ b2, const float* __restrict__ b3,
                          float* __restrict__ bcat)
{
    int i = blockIdx.x * 256 + threadIdx.x;
    if (i < 512) bcat[i] = b0[i];
    else if (i < 1024) bcat[i] = b1[i - 512];
    else if (i < 1536) bcat[i] = b2[i - 1024];
    else if (i < 2048) bcat[i] = b3[i - 1536];
}

// ---------------- split-bf16 MFMA GEMM: M=4096, K=512 ----------------
template<int MODE>
__global__ __launch_bounds__(256)
void gemm_mfma(const u16* __restrict__ Ah, const u16* __restrict__ Al,
               const u16* __restrict__ BTh, const u16* __restrict__ BTl,
               const float* __restrict__ bias, float* __restrict__ C,
               const float* __restrict__ G, int gstride, int N)
{
    __shared__ __align__(16) u16 AsH[128 * 40], AsL[128 * 40], BsH[64 * 40], BsL[64 * 40];
    const int tid = threadIdx.x;
    const int m0 = blockIdx.y * 128, n0 = blockIdx.x * 64;
    const int wid = tid >> 6, lane = tid & 63;
    const int wm = (wid >> 1) * 64, wn = (wid & 1) * 32;
    const int lr = lane & 15, lg = lane >> 4;

    f32x4 acc[4][2];
    #pragma unroll
    for (int i = 0; i < 4; ++i)
        #pragma unroll
        for (int j = 0; j < 2; ++j) acc[i][j] = (f32x4){0.f, 0.f, 0.f, 0.f};

    const int r0 = tid >> 2, s = tid & 3;

    for (int k0 = 0; k0 < 512; k0 += 32) {
        __syncthreads();
        size_t ga = (size_t)(m0 + r0) * 512 + k0 + s * 8;
        *(uint4*)&AsH[r0 * 40 + s * 8] = *(const uint4*)(Ah + ga);
        *(uint4*)&AsL[r0 * 40 + s * 8] = *(const uint4*)(Al + ga);
        size_t gb = (size_t)(m0 + r0 + 64) * 512 + k0 + s * 8;
        *(uint4*)&AsH[(r0 + 64) * 40 + s * 8] = *(const uint4*)(Ah + gb);
        *(uint4*)&AsL[(r0 + 64) * 40 + s * 8] = *(const uint4*)(Al + gb);
        size_t gc = (size_t)(n0 + r0) * 512 + k0 + s * 8;
        *(uint4*)&BsH[r0 * 40 + s * 8] = *(const uint4*)(BTh + gc);
        *(uint4*)&BsL[r0 * 40 + s * 8] = *(const uint4*)(BTl + gc);
        __syncthreads();

        bf16x8 ah[4], al[4], bh[2], bl[2];
        #pragma unroll
        for (int i = 0; i < 4; ++i) {
            int row = wm + i * 16 + lr;
            ah[i] = *(const bf16x8*)&AsH[row * 40 + lg * 8];
            al[i] = *(const bf16x8*)&AsL[row * 40 + lg * 8];
        }
        #pragma unroll
        for (int j = 0; j < 2; ++j) {
            int row = wn + j * 16 + lr;
            bh[j] = *(const bf16x8*)&BsH[row * 40 + lg * 8];
            bl[j] = *(const bf16x8*)&BsL[row * 40 + lg * 8];
        }
        #pragma unroll
        for (int i = 0; i < 4; ++i)
            #pragma unroll
            for (int j = 0; j < 2; ++j) {
                acc[i][j] = __builtin_amdgcn_mfma_f32_16x16x32_bf16(ah[i], bh[j], acc[i][j], 0, 0, 0);
                acc[i][j] = __builtin_amdgcn_mfma_f32_16x16x32_bf16(ah[i], bl[j], acc[i][j], 0, 0, 0);
                acc[i][j] = __builtin_amdgcn_mfma_f32_16x16x32_bf16(al[i], bh[j], acc[i][j], 0, 0, 0);
            }
    }

    #pragma unroll
    for (int i = 0; i < 4; ++i)
        #pragma unroll
        for (int j = 0; j < 2; ++j) {
            int col = n0 + wn + j * 16 + lr;
            float bs = bias[col];
            #pragma unroll
            for (int r = 0; r < 4; ++r) {
                int row = m0 + wm + i * 16 + lg * 4 + r;
                float v = acc[i][j][r] + bs;
                size_t idx = (size_t)row * N + col;
                if (MODE == 0) C[idx] = v;
                else {
                    float g = G[(size_t)row * gstride + col];
                    C[idx] += v / (1.0f + __expf(-g));
                }
            }
        }
}

// ---------------- fp32 vector GEMM for the small matrices ----------------
template<int TM>
__global__ __launch_bounds__(256)
void gemm_k512(const float* __restrict__ A, const float* __restrict__ W,
               const float* __restrict__ bias, float* __restrict__ C,
               int M, int N)
{
    constexpr int BM = TM * 16;
    constexpr int BK = 32;
    __shared__ float As[BK][BM + 4];
    __shared__ float Bs[BK][64 + 4];
    const int tid = threadIdx.x;
    const int m0 = blockIdx.y * BM;
    const int n0 = blockIdx.x * 64;
    const int tm = tid >> 4, tn = tid & 15;
    float acc[TM][4];
    #pragma unroll
    for (int i = 0; i < TM; ++i)
        #pragma unroll
        for (int j = 0; j < 4; ++j) acc[i][j] = 0.f;

    for (int k0 = 0; k0 < 512; k0 += BK) {
        #pragma unroll
        for (int f = tid; f < BM * 8; f += 256) {
            int row = f >> 3, c4 = f & 7;
            float4 av = *(const float4*)(A + (size_t)(m0 + row) * 512 + k0 + c4 * 4);
            As[c4 * 4 + 0][row] = av.x;
            As[c4 * 4 + 1][row] = av.y;
            As[c4 * 4 + 2][row] = av.z;
            As[c4 * 4 + 3][row] = av.w;
        }
        #pragma unroll
        for (int f = tid; f < 512; f += 256) {
            int row = f >> 4, c4 = f & 15;
            *(float4*)(&Bs[row][c4 * 4]) = *(const float4*)(W + (size_t)(k0 + row) * N + n0 + c4 * 4);
        }
        __syncthreads();
        #pragma unroll
        for (int kk = 0; kk < BK; ++kk) {
            float a[TM], bb[4];
            #pragma unroll
            for (int i4 = 0; i4 < TM / 4; ++i4)
                *(float4*)(&a[i4 * 4]) = *(const float4*)(&As[kk][tm * TM + i4 * 4]);
            *(float4*)(bb) = *(const float4*)(&Bs[kk][tn * 4]);
            #pragma unroll
            for (int i = 0; i < TM; ++i)
                #pragma unroll
                for (int j = 0; j < 4; ++j)
                    acc[i][j] += a[i] * bb[j];
        }
        __syncthreads();
    }
    #pragma unroll
    for (int i = 0; i < TM; ++i) {
        int m = m0 + tm * TM + i;
        #pragma unroll
        for (int j = 0; j < 4; ++j) {
            int n = n0 + tn * 4 + j;
            C[(size_t)m * N + n] = acc[i][j] + bias[n];
        }
    }
}

// ---------------- mean-pool x over groups of 8 tokens (first 1536) ----------------
__global__ void pool_x(const float* __restrict__ x, float* __restrict__ comp)
{
    int row = blockIdx.x;
    int b = row / NPOOLS, p = row % NPOOLS;
    const float* src = x + ((size_t)b * SEQ + (size_t)p * RATIO) * DM;
    float* dst = comp + (size_t)row * DM;
    for (int d = threadIdx.x; d < DM; d += 256) {
        float sv = 0.f;
        #pragma unroll
        for (int r = 0; r < RATIO; ++r) sv += src[(size_t)r * DM + d];
        dst[d] = sv * 0.125f;
    }
}

// ---------------- importance GEMV ----------------
__global__ __launch_bounds__(256)
void gemv_imp(const float* __restrict__ x, const float* __restrict__ w,
              const float* __restrict__ bsc, float* __restrict__ imp)
{
    int row = blockIdx.x * 4 + (threadIdx.x >> 6);
    int lane = threadIdx.x & 63;
    const float* xr = x + (size_t)row * DM;
    float sv = 0.f;
    #pragma unroll
    for (int i = 0; i < 8; ++i) sv += xr[lane + i * 64] * w[lane + i * 64];
    #pragma unroll
    for (int off = 32; off; off >>= 1) sv += __shfl_xor(sv, off);
    if (lane == 0) imp[row] = sv + bsc[0];
}

// ---------------- top-64 per batch ----------------
__global__ __launch_bounds__(64)
void topk_sel(const float* __restrict__ imp, int* __restrict__ tidx)
{
    __shared__ float vals[SEQ];
    int b = blockIdx.x;
    int lane = threadIdx.x;
    for (int i = lane; i < SEQ; i += 64) vals[i] = imp[(size_t)b * SEQ + i];
    __syncthreads();
    for (int r = 0; r < TOPKN; ++r) {
        float bv = -1e30f; int bi = 0x7fffffff;
        for (int i = lane; i < SEQ; i += 64) {
            float v = vals[i];
            if (v > bv) { bv = v; bi = i; }
        }
        #pragma unroll
        for (int off = 32; off; off >>= 1) {
            float ov = __shfl_xor(bv, off);
            int oi = __shfl_xor(bi, off);
            if (ov > bv || (ov == bv && oi < bi)) { bv = ov; bi = oi; }
        }
        if (lane == 0) {
            tidx[b * TOPKN + r] = bi;
            vals[bi] = -1e30f;
        }
        __syncthreads();
    }
}

// ---------------- gather selected rows of x ----------------
__global__ void gather_sel(const float* __restrict__ x, const int* __restrict__ tidx,
                           float* __restrict__ sel)
{
    int r = blockIdx.x;
    int b = r >> 6;
    int t = tidx[r];
    const float* src = x + ((size_t)b * SEQ + t) * DM;
    float* dst = sel + (size_t)r * DM;
    for (int j = threadIdx.x; j < DM; j += 256) dst[j] = src[j];
}

// =====================================================================
// Attention v3 (MFMA flash, split-bf16): block = 64 queries x 1 head;
// 4 waves x 16-query strips; K-tiles of 64 keys in LDS (stride-72 rows),
// V transposed [d][key]; P transposed through LDS (aliases K buffer).
// No max-subtraction (validated in v1/v2): partials additive across tiles.
// BRANCH: 0=local window, 1=compressed pools, 2=topk selected.
// =====================================================================
template<int BRANCH>
__global__ __launch_bounds__(256)
void attn_mfma(const float* __restrict__ Qsrc, const float* __restrict__ Ksrc,
               const float* __restrict__ Vsrc, const int* __restrict__ tidx,
               u16* __restrict__ oh, u16* __restrict__ ol)
{
    __shared__ __align__(16) u16 Kh[64 * 72], Kl[64 * 72], VTh[64 * 72], VTl[64 * 72];
    const int tid = threadIdx.x;
    const int w = tid >> 6, lane = tid & 63;
    const int lr = lane & 15, lg = lane >> 4;
    const int qb = blockIdx.x, h = blockIdx.y, b = blockIdx.z;
    const int q0 = qb * 64;
    const int qrow0 = q0 + w * 16;

    // ---- load Q fragments (A-layout: row = lr, k = lg*8 within 32-step) ----
    const int QSTRIDE = (BRANCH == 0) ? 1536 : 2048;
    const int qcol = (BRANCH == 2) ? 512 + h * HDIM : h * HDIM;
    const float* qrow = Qsrc + (size_t)(b * SEQ + qrow0 + lr) * QSTRIDE + qcol;
    bf16x8 Qh[2], Ql[2];
    #pragma unroll
    for (int ks = 0; ks < 2; ++ks) {
        int d0 = ks * 32 + lg * 8;
        float4 a = *(const float4*)(qrow + d0);
        float4 bq = *(const float4*)(qrow + d0 + 4);
        float v[8] = {a.x, a.y, a.z, a.w, bq.x, bq.y, bq.z, bq.w};
        u16 hs[8], ls[8];
        #pragma unroll
        for (int j = 0; j < 8; ++j) {
            float sv = v[j] * 0.125f;
            hs[j] = f2bf(sv);
            ls[j] = f2bf(sv - bf2f(hs[j]));
        }
        Qh[ks] = *(bf16x8*)hs;
        Ql[ks] = *(bf16x8*)ls;
    }

    // ---- topk mask data ----
    int tj[4]; int tmin = 0x7fffffff;
    if (BRANCH == 2) {
        #pragma unroll
        for (int nf = 0; nf < 4; ++nf) {
            tj[nf] = tidx[b * TOPKN + nf * 16 + lr];
            tmin = imini(tmin, tj[nf]);
        }
        tmin = imini(tmin, __shfl_xor(tmin, 1));
        tmin = imini(tmin, __shfl_xor(tmin, 2));
        tmin = imini(tmin, __shfl_xor(tmin, 4));
        tmin = imini(tmin, __shfl_xor(tmin, 8));
    }

    int t0 = 0, t1 = 0;
    if (BRANCH == 0) { t0 = imaxi(0, qb - 8); t1 = qb; }
    else if (BRANCH == 1) { t0 = 0; t1 = 2; }

    f32x4 onf[4];
    #pragma unroll
    for (int i = 0; i < 4; ++i) onf[i] = (f32x4){0.f, 0.f, 0.f, 0.f};
    f32x4 lvec = (f32x4){0.f, 0.f, 0.f, 0.f};

    const int r_ = tid >> 2, c4 = tid & 3;        // K staging: row, 16-dim chunk
    const int dd = tid >> 2, k4 = (tid & 3) * 16; // V staging: dim row, 16-key chunk

    for (int t = t0; t <= t1; ++t) {
        const int kb = t * 64;
        __syncthreads();  // prior tile's K (aliased by P) & VT fully consumed

        // ---- stage K tile: rows=key, cols=d, bf16 hi/lo ----
        {
            const float* kr;
            if (BRANCH == 0)
                kr = Ksrc + (size_t)(b * SEQ + kb + r_) * 1536 + 512 + h * HDIM + c4 * 16;
            else if (BRANCH == 1)
                kr = Ksrc + (size_t)(b * NPOOLS + kb + r_) * DM + h * HDIM + c4 * 16;
            else
                kr = Ksrc + (size_t)(b * TOPKN + r_) * DM + h * HDIM + c4 * 16;
            float vv[16];
            #pragma unroll
            for (int j4 = 0; j4 < 4; ++j4)
                *(float4*)(&vv[j4 * 4]) = *(const float4*)(kr + j4 * 4);
            u16 hs[16], ls[16];
            #pragma unroll
            for (int j = 0; j < 16; ++j) {
                hs[j] = f2bf(vv[j]);
                ls[j] = f2bf(vv[j] - bf2f(hs[j]));
            }
            *(uint4*)&Kh[r_ * 72 + c4 * 16]     = ((uint4*)hs)[0];
            *(uint4*)&Kh[r_ * 72 + c4 * 16 + 8] = ((uint4*)hs)[1];
            *(uint4*)&Kl[r_ * 72 + c4 * 16]     = ((uint4*)ls)[0];
            *(uint4*)&Kl[r_ * 72 + c4 * 16 + 8] = ((uint4*)ls)[1];
        }
        // ---- stage V transposed: VT[d][key], bf16 hi/lo ----
        {
            const float* vb;
            int RS;
            if (BRANCH == 0) { vb = Vsrc + (size_t)(b * SEQ + kb + k4) * 1536 + 1024 + h * HDIM + dd; RS = 1536; }
            else if (BRANCH == 1) { vb = Vsrc + (size_t)(b * NPOOLS + kb + k4) * DM + h * HDIM + dd; RS = DM; }
            else { vb = Vsrc + (size_t)(b * TOPKN + k4) * DM + h * HDIM + dd; RS = DM; }
            u16 hs[16], ls[16];
            #pragma unroll
            for (int j = 0; j < 16; ++j) {
                float v = vb[(size_t)j * RS];
                hs[j] = f2bf(v);
                ls[j] = f2bf(v - bf2f(hs[j]));
            }
            *(uint4*)&VTh[dd * 72 + k4]     = ((uint4*)hs)[0];
            *(uint4*)&VTh[dd * 72 + k4 + 8] = ((uint4*)hs)[1];
            *(uint4*)&VTl[dd * 72 + k4]     = ((uint4*)ls)[0];
            *(uint4*)&VTl[dd * 72 + k4 + 8] = ((uint4*)ls)[1];
        }
        __syncthreads();

        // ---- S = Q @ K^T (split-bf16, 3 planes) ----
        f32x4 sf[4];
        #pragma unroll
        for (int nf = 0; nf < 4; ++nf) {
            sf[nf] = (f32x4){0.f, 0.f, 0.f, 0.f};
            #pragma unroll
            for (int ks = 0; ks < 2; ++ks) {
                bf16x8 bh = *(const bf16x8*)&Kh[(nf * 16 + lr) * 72 + ks * 32 + lg * 8];
                bf16x8 bl = *(const bf16x8*)&Kl[(nf * 16 + lr) * 72 + ks * 32 + lg * 8];
                sf[nf] = __builtin_amdgcn_mfma_f32_16x16x32_bf16(Qh[ks], bh, sf[nf], 0, 0, 0);
                sf[nf] = __builtin_amdgcn_mfma_f32_16x16x32_bf16(Qh[ks], bl, sf[nf], 0, 0, 0);
                sf[nf] = __builtin_amdgcn_mfma_f32_16x16x32_bf16(Ql[ks], bh, sf[nf], 0, 0, 0);
            }
        }
        __syncthreads();  // all waves done reading K -> P may overwrite it

        // ---- mask + exp + write P (hi/lo) into K-buffer alias ----
        u16* Ph = Kh + w * 1152;   // [16][72] per wave
        u16* Pl = Kl + w * 1152;
        #pragma unroll
        for (int nf = 0; nf < 4; ++nf) {
            #pragma unroll
            for (int rr = 0; rr < 4; ++rr) {
                int rq = qrow0 + lg * 4 + rr;     // global query row
                int ck = kb + nf * 16 + lr;       // global key index
                float s = sf[nf][rr];
                float p;
                if (BRANCH == 0) {
                    bool valid = (ck <= rq) && (rq - ck < WIN);
                    p = valid ? __expf(s) : 0.f;
                } else if (BRANCH == 1) {
                    bool valid = rq >= (ck + 1) * RATIO;
                    p = (rq < RATIO) ? 1.f : (valid ? __expf(s) : 0.f);
                } else {
                    bool valid = rq >= tj[nf];
                    p = (rq < tmin) ? 1.f : (valid ? __expf(s) : 0.f);
                }
                lvec[rr] += p;
                u16 ph_ = f2bf(p);
                Ph[(lg * 4 + rr) * 72 + nf * 16 + lr] = ph_;
                Pl[(lg * 4 + rr) * 72 + nf * 16 + lr] = f2bf(p - bf2f(ph_));
            }
        }

        // ---- O += P @ V (split-bf16, 3 planes); wave-private P ----
        bf16x8 pah[2], pal[2];
        #pragma unroll
        for (int ks2 = 0; ks2 < 2; ++ks2) {
            pah[ks2] = *(const bf16x8*)&Ph[lr * 72 + ks2 * 32 + lg * 8];
            pal[ks2] = *(const bf16x8*)&Pl[lr * 72 + ks2 * 32 + lg * 8];
        }
        #pragma unroll
        for (int nd = 0; nd < 4; ++nd) {
            #pragma unroll
            for (int ks2 = 0; ks2 < 2; ++ks2) {
                bf16x8 vh = *(const bf16x8*)&VTh[(nd * 16 + lr) * 72 + ks2 * 32 + lg * 8];
                bf16x8 vl = *(const bf16x8*)&VTl[(nd * 16 + lr) * 72 + ks2 * 32 + lg * 8];
                onf[nd] = __builtin_amdgcn_mfma_f32_16x16x32_bf16(pah[ks2], vh, onf[nd], 0, 0, 0);
                onf[nd] = __builtin_amdgcn_mfma_f32_16x16x32_bf16(pah[ks2], vl, onf[nd], 0, 0, 0);
                onf[nd] = __builtin_amdgcn_mfma_f32_16x16x32_bf16(pal[ks2], vh, onf[nd], 0, 0, 0);
            }
        }
    }

    // ---- reduce l across the 16 col-lanes (lr bits), normalize, store ----
    #pragma unroll
    for (int bit = 1; bit <= 8; bit <<= 1) {
        lvec[0] += __shfl_xor(lvec[0], bit);
        lvec[1] += __shfl_xor(lvec[1], bit);
        lvec[2] += __shfl_xor(lvec[2], bit);
        lvec[3] += __shfl_xor(lvec[3], bit);
    }
    f32x4 inv;
    #pragma unroll
    for (int rr = 0; rr < 4; ++rr) inv[rr] = 1.0f / lvec[rr];

    #pragma unroll
    for (int nd = 0; nd < 4; ++nd) {
        #pragma unroll
        for (int rr = 0; rr < 4; ++rr) {
            int row = b * SEQ + qrow0 + lg * 4 + rr;
            size_t idx = (size_t)row * DM + h * HDIM + nd * 16 + lr;
            float v = onf[nd][rr] * inv[rr];
            u16 hv = f2bf(v);
            oh[idx] = hv;
            ol[idx] = f2bf(v - bf2f(hv));
        }
    }
}

extern "C" void kernel_launch(void* const* d_in, const int* in_sizes, int n_in,
                              void* d_out, int out_size, void* d_ws, size_t ws_size,
                              hipStream_t stream)
{
    const float* x      = (const float*)d_in[0];
    const float* lqkv_W = (const float*)d_in[1];
    const float* lqkv_b = (const float*)d_in[2];
    const float* lout_W = (const float*)d_in[3];
    const float* lout_b = (const float*)d_in[4];
    const float* cq_W   = (const float*)d_in[5];
    const float* cq_b   = (const float*)d_in[6];
    const float* ck_W   = (const float*)d_in[7];
    const float* ck_b   = (const float*)d_in[8];
    const float* cv_W   = (const float*)d_in[9];
    const float* cv_b   = (const float*)d_in[10];
    const float* cout_W = (const float*)d_in[11];
    const float* cout_b = (const float*)d_in[12];
    const float* gc_W   = (const float*)d_in[13];
    const float* gc_b   = (const float*)d_in[14];
    const float* imp_W  = (const float*)d_in[15];
    const float* imp_b  = (const float*)d_in[16];
    const float* tq_W   = (const float*)d_in[17];
    const float* tq_b   = (const float*)d_in[18];
    const float* tk_W   = (const float*)d_in[19];
    const float* tk_b   = (const float*)d_in[20];
    const float* tv_W   = (const float*)d_in[21];
    const float* tv_b   = (const float*)d_in[22];
    const float* tout_W = (const float*)d_in[23];
    const float* tout_b = (const float*)d_in[24];
    const float* gt_W   = (const float*)d_in[25];
    const float* gt_b   = (const float*)d_in[26];
    float* out = (float*)d_out;

    char* wsb = (char*)d_ws;
    size_t off = 0;
    auto carve = [&](size_t bytes) { void* p = wsb + off; off += (bytes + 255) & ~(size_t)255; return p; };
    float* qkv   = (float*)carve(4096ull * 1536 * 4);
    float* fq    = (float*)carve(4096ull * 2048 * 4);
    u16*   xh    = (u16*)  carve(4096ull * 512 * 2);
    u16*   xl    = (u16*)  carve(4096ull * 512 * 2);
    u16*   WqkvTh= (u16*)  carve(1536ull * 512 * 2);
    u16*   WqkvTl= (u16*)  carve(1536ull * 512 * 2);
    u16*   WcatTh= (u16*)  carve(2048ull * 512 * 2);
    u16*   WcatTl= (u16*)  carve(2048ull * 512 * 2);
    u16*   WLoTh = (u16*)  carve(512ull * 512 * 2);
    u16*   WLoTl = (u16*)  carve(512ull * 512 * 2);
    u16*   WCoTh = (u16*)  carve(512ull * 512 * 2);
    u16*   WCoTl = (u16*)  carve(512ull * 512 * 2);
    u16*   WToTh = (u16*)  carve(512ull * 512 * 2);
    u16*   WToTl = (u16*)  carve(512ull * 512 * 2);
    float* bcat  = (float*)carve(2048ull * 4);
    float* comp  = (float*)carve(384ull * 512 * 4);
    float* kc    = (float*)carve(384ull * 512 * 4);
    float* vc    = (float*)carve(384ull * 512 * 4);
    float* impb  = (float*)carve(4096ull * 4);
    int*   tidx  = (int*)  carve(128ull * 4);
    float* sel   = (float*)carve(128ull * 512 * 4);
    float* kt    = (float*)carve(128ull * 512 * 4);
    float* vt    = (float*)carve(128ull * 512 * 4);
    u16*   aLh   = (u16*)  carve(4096ull * 512 * 2);
    u16*   aLl   = (u16*)  carve(4096ull * 512 * 2);
    u16*   aCh   = (u16*)  carve(4096ull * 512 * 2);
    u16*   aCl   = (u16*)  carve(4096ull * 512 * 2);
    u16*   aTh   = (u16*)  carve(4096ull * 512 * 2);
    u16*   aTl   = (u16*)  carve(4096ull * 512 * 2);

    // ---- conversions ----
    conv_act<<<1024, 256, 0, stream>>>(x, xh, xl, 4096 * 512 / 8);
    conv_wT<<<dim3(24, 8), 256, 0, stream>>>(lqkv_W, 1536, WqkvTh, WqkvTl, 0);
    conv_wT<<<dim3(8, 8), 256, 0, stream>>>(cq_W, 512, WcatTh, WcatTl, 0);
    conv_wT<<<dim3(8, 8), 256, 0, stream>>>(tq_W, 512, WcatTh, WcatTl, 512);
    conv_wT<<<dim3(8, 8), 256, 0, stream>>>(gc_W, 512, WcatTh, WcatTl, 1024);
    conv_wT<<<dim3(8, 8), 256, 0, stream>>>(gt_W, 512, WcatTh, WcatTl, 1536);
    conv_wT<<<dim3(8, 8), 256, 0, stream>>>(lout_W, 512, WLoTh, WLoTl, 0);
    conv_wT<<<dim3(8, 8), 256, 0, stream>>>(cout_W, 512, WCoTh, WCoTl, 0);
    conv_wT<<<dim3(8, 8), 256, 0, stream>>>(tout_W, 512, WToTh, WToTl, 0);
    bcat_fill<<<8, 256, 0, stream>>>(cq_b, tq_b, gc_b, gt_b, bcat);

    // ---- big projections via split-bf16 MFMA ----
    gemm_mfma<0><<<dim3(24, 32), 256, 0, stream>>>(xh, xl, WqkvTh, WqkvTl, lqkv_b, qkv, nullptr, 0, 1536);
    gemm_mfma<0><<<dim3(32, 32), 256, 0, stream>>>(xh, xl, WcatTh, WcatTl, bcat, fq, nullptr, 0, 2048);

    // ---- pooling + compressed K/V ----
    pool_x<<<384, 256, 0, stream>>>(x, comp);
    gemm_k512<4><<<dim3(8, 6), 256, 0, stream>>>(comp, ck_W, ck_b, kc, 384, 512);
    gemm_k512<4><<<dim3(8, 6), 256, 0, stream>>>(comp, cv_W, cv_b, vc, 384, 512);

    // ---- importance + top-k + gather + selected K/V ----
    gemv_imp<<<1024, 256, 0, stream>>>(x, imp_W, imp_b, impb);
    topk_sel<<<2, 64, 0, stream>>>(impb, tidx);
    gather_sel<<<128, 256, 0, stream>>>(x, tidx, sel);
    gemm_k512<4><<<dim3(8, 2), 256, 0, stream>>>(sel, tk_W, tk_b, kt, 128, 512);
    gemm_k512<4><<<dim3(8, 2), 256, 0, stream>>>(sel, tv_W, tv_b, vt, 128, 512);

    // ---- attention v3: MFMA flash (split-bf16) ----
    attn_mfma<0><<<dim3(32, 8, 2), 256, 0, stream>>>(qkv, qkv, qkv, nullptr, aLh, aLl);
    attn_mfma<1><<<dim3(32, 8, 2), 256, 0, stream>>>(fq, kc, vc, nullptr, aCh, aCl);
    attn_mfma<2><<<dim3(32, 8, 2), 256, 0, stream>>>(fq, kt, vt, tidx, aTh, aTl);

    // ---- output projections: out = projL + sig(gC)*projC + sig(gT)*projT ----
    gemm_mfma<0><<<dim3(8, 32), 256, 0, stream>>>(aLh, aLl, WLoTh, WLoTl, lout_b, out, nullptr, 0, 512);
    gemm_mfma<1><<<dim3(8, 32), 256, 0, stream>>>(aCh, aCl, WCoTh, WCoTl, cout_b, out, fq + 1024, 2048, 512);
    gemm_mfma<1><<<dim3(8, 32), 256, 0, stream>>>(aTh, aTl, WToTh, WToTl, tout_b, out, fq + 1536, 2048, 512);
}

// Round 7
// 524.854 us; speedup vs baseline: 2.9416x; 1.1439x over previous
//
#include <hip/hip_runtime.h>
#include <cstdint>
#include <cstddef>

#define HNUM 8
#define HDIM 64
#define WIN 512
#define RATIO 8
#define TOPKN 64
#define BATCH 2
#define SEQ 2048
#define DM 512
#define NPOOLS 192
#define NEGV (-1000000000.0f)

typedef unsigned short u16;
typedef __attribute__((ext_vector_type(8))) short bf16x8;
typedef __attribute__((ext_vector_type(4))) float f32x4;

static __device__ __forceinline__ int imaxi(int a, int b){ return a > b ? a : b; }
static __device__ __forceinline__ int imini(int a, int b){ return a < b ? a : b; }

// bf16 round-to-nearest-even via bit ops (inputs finite)
static __device__ __forceinline__ u16 f2bf(float v) {
    union { float f; uint32_t u; } c; c.f = v;
    uint32_t r = c.u + 0x7fffu + ((c.u >> 16) & 1u);
    return (u16)(r >> 16);
}
static __device__ __forceinline__ float bf2f(u16 u) {
    union { uint32_t u; float f; } c; c.u = ((uint32_t)u) << 16;
    return c.f;
}

// ---------------- fp32 -> (hi, lo) bf16 planes, elementwise ----------------
__global__ __launch_bounds__(256)
void conv_act(const float* __restrict__ in, u16* __restrict__ h, u16* __restrict__ l, int n8)
{
    int i = blockIdx.x * 256 + threadIdx.x;
    if (i >= n8) return;
    const float4* p = (const float4*)(in + (size_t)i * 8);
    float4 a = p[0], b = p[1];
    float v[8] = {a.x, a.y, a.z, a.w, b.x, b.y, b.z, b.w};
    u16 hs[8], ls[8];
    #pragma unroll
    for (int j = 0; j < 8; ++j) {
        hs[j] = f2bf(v[j]);
        ls[j] = f2bf(v[j] - bf2f(hs[j]));
    }
    *(uint4*)(h + (size_t)i * 8) = *(uint4*)hs;
    *(uint4*)(l + (size_t)i * 8) = *(uint4*)ls;
}

// ------------- weight transpose-convert: W[512][N] -> WT planes [N][512] -------------
__global__ __launch_bounds__(256)
void conv_wT(const float* __restrict__ W, int N,
             u16* __restrict__ WTh, u16* __restrict__ WTl, int dstRowOff)
{
    __shared__ float t[64][65];
    const int n0 = blockIdx.x * 64, k0 = blockIdx.y * 64;
    const int tid = threadIdx.x;
    const int tk = tid >> 4, tn = (tid & 15) * 4;
    #pragma unroll
    for (int r = 0; r < 4; ++r) {
        int k = tk + r * 16;
        float4 v = *(const float4*)(W + (size_t)(k0 + k) * N + n0 + tn);
        t[k][tn + 0] = v.x; t[k][tn + 1] = v.y; t[k][tn + 2] = v.z; t[k][tn + 3] = v.w;
    }
    __syncthreads();
    const int nl = tid >> 2, s = tid & 3;
    u16 hs[16], ls[16];
    #pragma unroll
    for (int j = 0; j < 16; ++j) {
        float v = t[s * 16 + j][nl];
        hs[j] = f2bf(v);
        ls[j] = f2bf(v - bf2f(hs[j]));
    }
    size_t base = (size_t)(dstRowOff + n0 + nl) * 512 + k0 + s * 16;
    *(uint4*)(WTh + base)     = ((uint4*)hs)[0];
    *(uint4*)(WTh + base + 8) = ((uint4*)hs)[1];
    *(uint4*)(WTl + base)     = ((uint4*)ls)[0];
    *(uint4*)(WTl + base + 8) = ((uint4*)ls)[1];
}

// ------------- 7x (512x512) weight transpose-convert in one launch -------------
__global__ __launch_bounds__(256)
void conv_wT7(const float* __restrict__ w0, const float* __restrict__ w1,
              const float* __restrict__ w2, const float* __restrict__ w3,
              const float* __restrict__ w4, const float* __restrict__ w5,
              const float* __restrict__ w6,
              u16* __restrict__ WcatTh, u16* __restrict__ WcatTl,
              u16* __restrict__ WLoTh, u16* __restrict__ WLoTl,
              u16* __restrict__ WCoTh, u16* __restrict__ WCoTl,
              u16* __restrict__ WToTh, u16* __restrict__ WToTl)
{
    const float* W; u16* dh; u16* dl; int rowoff = 0;
    switch (blockIdx.z) {
        case 0: W = w0; dh = WcatTh; dl = WcatTl; rowoff = 0;    break;
        case 1: W = w1; dh = WcatTh; dl = WcatTl; rowoff = 512;  break;
        case 2: W = w2; dh = WcatTh; dl = WcatTl; rowoff = 1024; break;
        case 3: W = w3; dh = WcatTh; dl = WcatTl; rowoff = 1536; break;
        case 4: W = w4; dh = WLoTh;  dl = WLoTl;  rowoff = 0;    break;
        case 5: W = w5; dh = WCoTh;  dl = WCoTl;  rowoff = 0;    break;
        default: W = w6; dh = WToTh; dl = WToTl;  rowoff = 0;    break;
    }
    __shared__ float t[64][65];
    const int n0 = blockIdx.x * 64, k0 = blockIdx.y * 64;
    const int tid = threadIdx.x;
    const int tk = tid >> 4, tn = (tid & 15) * 4;
    #pragma unroll
    for (int r = 0; r < 4; ++r) {
        int k = tk + r * 16;
        float4 v = *(const float4*)(W + (size_t)(k0 + k) * 512 + n0 + tn);
        t[k][tn + 0] = v.x; t[k][tn + 1] = v.y; t[k][tn + 2] = v.z; t[k][tn + 3] = v.w;
    }
    __syncthreads();
    const int nl = tid >> 2, s = tid & 3;
    u16 hs[16], ls[16];
    #pragma unroll
    for (int j = 0; j < 16; ++j) {
        float v = t[s * 16 + j][nl];
        hs[j] = f2bf(v);
        ls[j] = f2bf(v - bf2f(hs[j]));
    }
    size_t base = (size_t)(rowoff + n0 + nl) * 512 + k0 + s * 16;
    *(uint4*)(dh + base)     = ((uint4*)hs)[0];
    *(uint4*)(dh + base + 8) = ((uint4*)hs)[1];
    *(uint4*)(dl + base)     = ((uint4*)ls)[0];
    *(uint4*)(dl + base + 8) = ((uint4*)ls)[1];
}

// ---------------- bias concat for fused q/gate GEMM ----------------
__global__ void bcat_fill(const float* __restrict__ b0, const float* __restrict__ b1,
                          const float* __restrict__ b2, const float* __restrict__ b3,
                          float* __restrict__ bcat)
{
    int i = blockIdx.x * 256 + threadIdx.x;
    if (i < 512) bcat[i] = b0[i];
    else if (i < 1024) bcat[i] = b1[i - 512];
    else if (i < 1536) bcat[i] = b2[i - 1024];
    else if (i < 2048) bcat[i] = b3[i - 1536];
}

// ---------------- split-bf16 MFMA GEMM: tile 128x128, K=512 ----------------
// MODE 0: C = A@B + bias   |   MODE 1: C += sigmoid(G) * (A@B + bias)
template<int MODE>
__global__ __launch_bounds__(256)
void gemm_mfma(const u16* __restrict__ Ah, const u16* __restrict__ Al,
               const u16* __restrict__ BTh, const u16* __restrict__ BTl,
               const float* __restrict__ bias, float* __restrict__ C,
               const float* __restrict__ G, int gstride, int N)
{
    __shared__ __align__(16) u16 AsH[128 * 40], AsL[128 * 40], BsH[128 * 40], BsL[128 * 40];
    const int tid = threadIdx.x;
    const int m0 = blockIdx.y * 128, n0 = blockIdx.x * 128;
    const int wid = tid >> 6, lane = tid & 63;
    const int wm = (wid >> 1) * 64, wn = (wid & 1) * 64;
    const int lr = lane & 15, lg = lane >> 4;

    f32x4 acc[4][4];
    #pragma unroll
    for (int i = 0; i < 4; ++i)
        #pragma unroll
        for (int j = 0; j < 4; ++j) acc[i][j] = (f32x4){0.f, 0.f, 0.f, 0.f};

    const int r0 = tid >> 2, s = tid & 3;

    for (int k0 = 0; k0 < 512; k0 += 32) {
        __syncthreads();
        size_t ga = (size_t)(m0 + r0) * 512 + k0 + s * 8;
        *(uint4*)&AsH[r0 * 40 + s * 8] = *(const uint4*)(Ah + ga);
        *(uint4*)&AsL[r0 * 40 + s * 8] = *(const uint4*)(Al + ga);
        size_t ga2 = (size_t)(m0 + r0 + 64) * 512 + k0 + s * 8;
        *(uint4*)&AsH[(r0 + 64) * 40 + s * 8] = *(const uint4*)(Ah + ga2);
        *(uint4*)&AsL[(r0 + 64) * 40 + s * 8] = *(const uint4*)(Al + ga2);
        size_t gb = (size_t)(n0 + r0) * 512 + k0 + s * 8;
        *(uint4*)&BsH[r0 * 40 + s * 8] = *(const uint4*)(BTh + gb);
        *(uint4*)&BsL[r0 * 40 + s * 8] = *(const uint4*)(BTl + gb);
        size_t gb2 = (size_t)(n0 + r0 + 64) * 512 + k0 + s * 8;
        *(uint4*)&BsH[(r0 + 64) * 40 + s * 8] = *(const uint4*)(BTh + gb2);
        *(uint4*)&BsL[(r0 + 64) * 40 + s * 8] = *(const uint4*)(BTl + gb2);
        __syncthreads();

        bf16x8 ah[4], al[4], bh[4], bl[4];
        #pragma unroll
        for (int i = 0; i < 4; ++i) {
            int row = wm + i * 16 + lr;
            ah[i] = *(const bf16x8*)&AsH[row * 40 + lg * 8];
            al[i] = *(const bf16x8*)&AsL[row * 40 + lg * 8];
        }
        #pragma unroll
        for (int j = 0; j < 4; ++j) {
            int row = wn + j * 16 + lr;
            bh[j] = *(const bf16x8*)&BsH[row * 40 + lg * 8];
            bl[j] = *(const bf16x8*)&BsL[row * 40 + lg * 8];
        }
        #pragma unroll
        for (int i = 0; i < 4; ++i)
            #pragma unroll
            for (int j = 0; j < 4; ++j) {
                acc[i][j] = __builtin_amdgcn_mfma_f32_16x16x32_bf16(ah[i], bh[j], acc[i][j], 0, 0, 0);
                acc[i][j] = __builtin_amdgcn_mfma_f32_16x16x32_bf16(ah[i], bl[j], acc[i][j], 0, 0, 0);
                acc[i][j] = __builtin_amdgcn_mfma_f32_16x16x32_bf16(al[i], bh[j], acc[i][j], 0, 0, 0);
            }
    }

    #pragma unroll
    for (int i = 0; i < 4; ++i)
        #pragma unroll
        for (int j = 0; j < 4; ++j) {
            int col = n0 + wn + j * 16 + lr;
            float bs = bias[col];
            #pragma unroll
            for (int r = 0; r < 4; ++r) {
                int row = m0 + wm + i * 16 + lg * 4 + r;
                float v = acc[i][j][r] + bs;
                size_t idx = (size_t)row * N + col;
                if (MODE == 0) C[idx] = v;
                else {
                    float g = G[(size_t)row * gstride + col];
                    C[idx] += v / (1.0f + __expf(-g));
                }
            }
        }
}

// ---------------- fp32 vector GEMM for the small matrices ----------------
template<int TM>
__global__ __launch_bounds__(256)
void gemm_k512(const float* __restrict__ A, const float* __restrict__ W,
               const float* __restrict__ bias, float* __restrict__ C,
               int M, int N)
{
    constexpr int BM = TM * 16;
    constexpr int BK = 32;
    __shared__ float As[BK][BM + 4];
    __shared__ float Bs[BK][64 + 4];
    const int tid = threadIdx.x;
    const int m0 = blockIdx.y * BM;
    const int n0 = blockIdx.x * 64;
    const int tm = tid >> 4, tn = tid & 15;
    float acc[TM][4];
    #pragma unroll
    for (int i = 0; i < TM; ++i)
        #pragma unroll
        for (int j = 0; j < 4; ++j) acc[i][j] = 0.f;

    for (int k0 = 0; k0 < 512; k0 += BK) {
        #pragma unroll
        for (int f = tid; f < BM * 8; f += 256) {
            int row = f >> 3, c4 = f & 7;
            float4 av = *(const float4*)(A + (size_t)(m0 + row) * 512 + k0 + c4 * 4);
            As[c4 * 4 + 0][row] = av.x;
            As[c4 * 4 + 1][row] = av.y;
            As[c4 * 4 + 2][row] = av.z;
            As[c4 * 4 + 3][row] = av.w;
        }
        #pragma unroll
        for (int f = tid; f < 512; f += 256) {
            int row = f >> 4, c4 = f & 15;
            *(float4*)(&Bs[row][c4 * 4]) = *(const float4*)(W + (size_t)(k0 + row) * N + n0 + c4 * 4);
        }
        __syncthreads();
        #pragma unroll
        for (int kk = 0; kk < BK; ++kk) {
            float a[TM], bb[4];
            #pragma unroll
            for (int i4 = 0; i4 < TM / 4; ++i4)
                *(float4*)(&a[i4 * 4]) = *(const float4*)(&As[kk][tm * TM + i4 * 4]);
            *(float4*)(bb) = *(const float4*)(&Bs[kk][tn * 4]);
            #pragma unroll
            for (int i = 0; i < TM; ++i)
                #pragma unroll
                for (int j = 0; j < 4; ++j)
                    acc[i][j] += a[i] * bb[j];
        }
        __syncthreads();
    }
    #pragma unroll
    for (int i = 0; i < TM; ++i) {
        int m = m0 + tm * TM + i;
        #pragma unroll
        for (int j = 0; j < 4; ++j) {
            int n = n0 + tn * 4 + j;
            C[(size_t)m * N + n] = acc[i][j] + bias[n];
        }
    }
}

// ---------------- mean-pool x over groups of 8 tokens (first 1536) ----------------
__global__ void pool_x(const float* __restrict__ x, float* __restrict__ comp)
{
    int row = blockIdx.x;
    int b = row / NPOOLS, p = row % NPOOLS;
    const float* src = x + ((size_t)b * SEQ + (size_t)p * RATIO) * DM;
    float* dst = comp + (size_t)row * DM;
    for (int d = threadIdx.x; d < DM; d += 256) {
        float sv = 0.f;
        #pragma unroll
        for (int r = 0; r < RATIO; ++r) sv += src[(size_t)r * DM + d];
        dst[d] = sv * 0.125f;
    }
}

// ---------------- importance GEMV ----------------
__global__ __launch_bounds__(256)
void gemv_imp(const float* __restrict__ x, const float* __restrict__ w,
              const float* __restrict__ bsc, float* __restrict__ imp)
{
    int row = blockIdx.x * 4 + (threadIdx.x >> 6);
    int lane = threadIdx.x & 63;
    const float* xr = x + (size_t)row * DM;
    float sv = 0.f;
    #pragma unroll
    for (int i = 0; i < 8; ++i) sv += xr[lane + i * 64] * w[lane + i * 64];
    #pragma unroll
    for (int off = 32; off; off >>= 1) sv += __shfl_xor(sv, off);
    if (lane == 0) imp[row] = sv + bsc[0];
}

// ---------------- top-64 per batch via full bitonic sort (2048 elems) ----------------
// Downstream use of tidx is set-invariant (masked-softmax sum over selected keys),
// so any order of the correct top-64 set works; comparator tie-breaks on lower
// index (matches lax.top_k selection on exact ties).
__global__ __launch_bounds__(1024)
void topk_bitonic(const float* __restrict__ imp, int* __restrict__ tidx)
{
    __shared__ float v[SEQ];
    __shared__ int ix[SEQ];
    const int b = blockIdx.x, tid = threadIdx.x;
    for (int i = tid; i < SEQ; i += 1024) { v[i] = imp[(size_t)b * SEQ + i]; ix[i] = i; }
    __syncthreads();
    for (int k = 2; k <= SEQ; k <<= 1) {
        for (int j = k >> 1; j > 0; j >>= 1) {
            for (int i = tid; i < SEQ; i += 1024) {
                int l = i ^ j;
                if (l > i) {
                    float vi = v[i], vl = v[l];
                    int ii = ix[i], il = ix[l];
                    // element-at-i belongs AFTER element-at-l in (desc value, asc index) order
                    bool iAfterL = (vi < vl) || (vi == vl && ii > il);
                    if (((i & k) == 0) == iAfterL) {
                        v[i] = vl; v[l] = vi; ix[i] = il; ix[l] = ii;
                    }
                }
            }
            __syncthreads();
        }
    }
    if (tid < TOPKN) tidx[b * TOPKN + tid] = ix[tid];
}

// ---------------- gather selected rows of x ----------------
__global__ void gather_sel(const float* __restrict__ x, const int* __restrict__ tidx,
                           float* __restrict__ sel)
{
    int r = blockIdx.x;
    int b = r >> 6;
    int t = tidx[r];
    const float* src = x + ((size_t)b * SEQ + t) * DM;
    float* dst = sel + (size_t)r * DM;
    for (int j = threadIdx.x; j < DM; j += 256) dst[j] = src[j];
}

// =====================================================================
// Attention (MFMA flash, split-bf16): block = 64 queries x 1 head;
// 4 waves x 16-query strips; K-tiles of 64 keys in LDS (stride-72 rows),
// V transposed [d][key]; P transposed through LDS (aliases K buffer).
// BRANCH: 0=local window, 1=compressed pools, 2=topk selected.
// =====================================================================
template<int BRANCH>
__global__ __launch_bounds__(256)
void attn_mfma(const float* __restrict__ Qsrc, const float* __restrict__ Ksrc,
               const float* __restrict__ Vsrc, const int* __restrict__ tidx,
               u16* __restrict__ oh, u16* __restrict__ ol)
{
    __shared__ __align__(16) u16 Kh[64 * 72], Kl[64 * 72], VTh[64 * 72], VTl[64 * 72];
    const int tid = threadIdx.x;
    const int w = tid >> 6, lane = tid & 63;
    const int lr = lane & 15, lg = lane >> 4;
    const int qb = blockIdx.x, h = blockIdx.y, b = blockIdx.z;
    const int q0 = qb * 64;
    const int qrow0 = q0 + w * 16;

    const int QSTRIDE = (BRANCH == 0) ? 1536 : 2048;
    const int qcol = (BRANCH == 2) ? 512 + h * HDIM : h * HDIM;
    const float* qrow = Qsrc + (size_t)(b * SEQ + qrow0 + lr) * QSTRIDE + qcol;
    bf16x8 Qh[2], Ql[2];
    #pragma unroll
    for (int ks = 0; ks < 2; ++ks) {
        int d0 = ks * 32 + lg * 8;
        float4 a = *(const float4*)(qrow + d0);
        float4 bq = *(const float4*)(qrow + d0 + 4);
        float v[8] = {a.x, a.y, a.z, a.w, bq.x, bq.y, bq.z, bq.w};
        u16 hs[8], ls[8];
        #pragma unroll
        for (int j = 0; j < 8; ++j) {
            float sv = v[j] * 0.125f;
            hs[j] = f2bf(sv);
            ls[j] = f2bf(sv - bf2f(hs[j]));
        }
        Qh[ks] = *(bf16x8*)hs;
        Ql[ks] = *(bf16x8*)ls;
    }

    int tj[4]; int tmin = 0x7fffffff;
    if (BRANCH == 2) {
        #pragma unroll
        for (int nf = 0; nf < 4; ++nf) {
            tj[nf] = tidx[b * TOPKN + nf * 16 + lr];
            tmin = imini(tmin, tj[nf]);
        }
        tmin = imini(tmin, __shfl_xor(tmin, 1));
        tmin = imini(tmin, __shfl_xor(tmin, 2));
        tmin = imini(tmin, __shfl_xor(tmin, 4));
        tmin = imini(tmin, __shfl_xor(tmin, 8));
    }

    int t0 = 0, t1 = 0;
    if (BRANCH == 0) { t0 = imaxi(0, qb - 8); t1 = qb; }
    else if (BRANCH == 1) { t0 = 0; t1 = (qb == 0) ? 2 : imini(2, (qb * 8 + 6) >> 6); }

    f32x4 onf[4];
    #pragma unroll
    for (int i = 0; i < 4; ++i) onf[i] = (f32x4){0.f, 0.f, 0.f, 0.f};
    f32x4 lvec = (f32x4){0.f, 0.f, 0.f, 0.f};

    const int r_ = tid >> 2, c4 = tid & 3;
    const int dd = tid >> 2, k4 = (tid & 3) * 16;

    for (int t = t0; t <= t1; ++t) {
        const int kb = t * 64;
        __syncthreads();

        {
            const float* kr;
            if (BRANCH == 0)
                kr = Ksrc + (size_t)(b * SEQ + kb + r_) * 1536 + 512 + h * HDIM + c4 * 16;
            else if (BRANCH == 1)
                kr = Ksrc + (size_t)(b * NPOOLS + kb + r_) * DM + h * HDIM + c4 * 16;
            else
                kr = Ksrc + (size_t)(b * TOPKN + r_) * DM + h * HDIM + c4 * 16;
            float vv[16];
            #pragma unroll
            for (int j4 = 0; j4 < 4; ++j4)
                *(float4*)(&vv[j4 * 4]) = *(const float4*)(kr + j4 * 4);
            u16 hs[16], ls[16];
            #pragma unroll
            for (int j = 0; j < 16; ++j) {
                hs[j] = f2bf(vv[j]);
                ls[j] = f2bf(vv[j] - bf2f(hs[j]));
            }
            *(uint4*)&Kh[r_ * 72 + c4 * 16]     = ((uint4*)hs)[0];
            *(uint4*)&Kh[r_ * 72 + c4 * 16 + 8] = ((uint4*)hs)[1];
            *(uint4*)&Kl[r_ * 72 + c4 * 16]     = ((uint4*)ls)[0];
            *(uint4*)&Kl[r_ * 72 + c4 * 16 + 8] = ((uint4*)ls)[1];
        }
        {
            const float* vb;
            int RS;
            if (BRANCH == 0) { vb = Vsrc + (size_t)(b * SEQ + kb + k4) * 1536 + 1024 + h * HDIM + dd; RS = 1536; }
            else if (BRANCH == 1) { vb = Vsrc + (size_t)(b * NPOOLS + kb + k4) * DM + h * HDIM + dd; RS = DM; }
            else { vb = Vsrc + (size_t)(b * TOPKN + k4) * DM + h * HDIM + dd; RS = DM; }
            u16 hs[16], ls[16];
            #pragma unroll
            for (int j = 0; j < 16; ++j) {
                float v = vb[(size_t)j * RS];
                hs[j] = f2bf(v);
                ls[j] = f2bf(v - bf2f(hs[j]));
            }
            *(uint4*)&VTh[dd * 72 + k4]     = ((uint4*)hs)[0];
            *(uint4*)&VTh[dd * 72 + k4 + 8] = ((uint4*)hs)[1];
            *(uint4*)&VTl[dd * 72 + k4]     = ((uint4*)ls)[0];
            *(uint4*)&VTl[dd * 72 + k4 + 8] = ((uint4*)ls)[1];
        }
        __syncthreads();

        f32x4 sf[4];
        #pragma unroll
        for (int nf = 0; nf < 4; ++nf) {
            sf[nf] = (f32x4){0.f, 0.f, 0.f, 0.f};
            #pragma unroll
            for (int ks = 0; ks < 2; ++ks) {
                bf16x8 bh = *(const bf16x8*)&Kh[(nf * 16 + lr) * 72 + ks * 32 + lg * 8];
                bf16x8 bl = *(const bf16x8*)&Kl[(nf * 16 + lr) * 72 + ks * 32 + lg * 8];
                sf[nf] = __builtin_amdgcn_mfma_f32_16x16x32_bf16(Qh[ks], bh, sf[nf], 0, 0, 0);
                sf[nf] = __builtin_amdgcn_mfma_f32_16x16x32_bf16(Qh[ks], bl, sf[nf], 0, 0, 0);
                sf[nf] = __builtin_amdgcn_mfma_f32_16x16x32_bf16(Ql[ks], bh, sf[nf], 0, 0, 0);
            }
        }
        __syncthreads();

        u16* Ph = Kh + w * 1152;
        u16* Pl = Kl + w * 1152;
        #pragma unroll
        for (int nf = 0; nf < 4; ++nf) {
            #pragma unroll
            for (int rr = 0; rr < 4; ++rr) {
                int rq = qrow0 + lg * 4 + rr;
                int ck = kb + nf * 16 + lr;
                float s = sf[nf][rr];
                float p;
                if (BRANCH == 0) {
                    bool valid = (ck <= rq) && (rq - ck < WIN);
                    p = valid ? __expf(s) : 0.f;
                } else if (BRANCH == 1) {
                    bool valid = rq >= (ck + 1) * RATIO;
                    p = (rq < RATIO) ? 1.f : (valid ? __expf(s) : 0.f);
                } else {
                    bool valid = rq >= tj[nf];
                    p = (rq < tmin) ? 1.f : (valid ? __expf(s) : 0.f);
                }
                lvec[rr] += p;
                u16 ph_ = f2bf(p);
                Ph[(lg * 4 + rr) * 72 + nf * 16 + lr] = ph_;
                Pl[(lg * 4 + rr) * 72 + nf * 16 + lr] = f2bf(p - bf2f(ph_));
            }
        }

        bf16x8 pah[2], pal[2];
        #pragma unroll
        for (int ks2 = 0; ks2 < 2; ++ks2) {
            pah[ks2] = *(const bf16x8*)&Ph[lr * 72 + ks2 * 32 + lg * 8];
            pal[ks2] = *(const bf16x8*)&Pl[lr * 72 + ks2 * 32 + lg * 8];
        }
        #pragma unroll
        for (int nd = 0; nd < 4; ++nd) {
            #pragma unroll
            for (int ks2 = 0; ks2 < 2; ++ks2) {
                bf16x8 vh = *(const bf16x8*)&VTh[(nd * 16 + lr) * 72 + ks2 * 32 + lg * 8];
                bf16x8 vl = *(const bf16x8*)&VTl[(nd * 16 + lr) * 72 + ks2 * 32 + lg * 8];
                onf[nd] = __builtin_amdgcn_mfma_f32_16x16x32_bf16(pah[ks2], vh, onf[nd], 0, 0, 0);
                onf[nd] = __builtin_amdgcn_mfma_f32_16x16x32_bf16(pah[ks2], vl, onf[nd], 0, 0, 0);
                onf[nd] = __builtin_amdgcn_mfma_f32_16x16x32_bf16(pal[ks2], vh, onf[nd], 0, 0, 0);
            }
        }
    }

    #pragma unroll
    for (int bit = 1; bit <= 8; bit <<= 1) {
        lvec[0] += __shfl_xor(lvec[0], bit);
        lvec[1] += __shfl_xor(lvec[1], bit);
        lvec[2] += __shfl_xor(lvec[2], bit);
        lvec[3] += __shfl_xor(lvec[3], bit);
    }
    f32x4 inv;
    #pragma unroll
    for (int rr = 0; rr < 4; ++rr) inv[rr] = 1.0f / lvec[rr];

    #pragma unroll
    for (int nd = 0; nd < 4; ++nd) {
        #pragma unroll
        for (int rr = 0; rr < 4; ++rr) {
            int row = b * SEQ + qrow0 + lg * 4 + rr;
            size_t idx = (size_t)row * DM + h * HDIM + nd * 16 + lr;
            float v = onf[nd][rr] * inv[rr];
            u16 hv = f2bf(v);
            oh[idx] = hv;
            ol[idx] = f2bf(v - bf2f(hv));
        }
    }
}

extern "C" void kernel_launch(void* const* d_in, const int* in_sizes, int n_in,
                              void* d_out, int out_size, void* d_ws, size_t ws_size,
                              hipStream_t stream)
{
    const float* x      = (const float*)d_in[0];
    const float* lqkv_W = (const float*)d_in[1];
    const float* lqkv_b = (const float*)d_in[2];
    const float* lout_W = (const float*)d_in[3];
    const float* lout_b = (const float*)d_in[4];
    const float* cq_W   = (const float*)d_in[5];
    const float* cq_b   = (const float*)d_in[6];
    const float* ck_W   = (const float*)d_in[7];
    const float* ck_b   = (const float*)d_in[8];
    const float* cv_W   = (const float*)d_in[9];
    const float* cv_b   = (const float*)d_in[10];
    const float* cout_W = (const float*)d_in[11];
    const float* cout_b = (const float*)d_in[12];
    const float* gc_W   = (const float*)d_in[13];
    const float* gc_b   = (const float*)d_in[14];
    const float* imp_W  = (const float*)d_in[15];
    const float* imp_b  = (const float*)d_in[16];
    const float* tq_W   = (const float*)d_in[17];
    const float* tq_b   = (const float*)d_in[18];
    const float* tk_W   = (const float*)d_in[19];
    const float* tk_b   = (const float*)d_in[20];
    const float* tv_W   = (const float*)d_in[21];
    const float* tv_b   = (const float*)d_in[22];
    const float* tout_W = (const float*)d_in[23];
    const float* tout_b = (const float*)d_in[24];
    const float* gt_W   = (const float*)d_in[25];
    const float* gt_b   = (const float*)d_in[26];
    float* out = (float*)d_out;

    char* wsb = (char*)d_ws;
    size_t off = 0;
    auto carve = [&](size_t bytes) { void* p = wsb + off; off += (bytes + 255) & ~(size_t)255; return p; };
    float* qkv   = (float*)carve(4096ull * 1536 * 4);
    float* fq    = (float*)carve(4096ull * 2048 * 4);
    u16*   xh    = (u16*)  carve(4096ull * 512 * 2);
    u16*   xl    = (u16*)  carve(4096ull * 512 * 2);
    u16*   WqkvTh= (u16*)  carve(1536ull * 512 * 2);
    u16*   WqkvTl= (u16*)  carve(1536ull * 512 * 2);
    u16*   WcatTh= (u16*)  carve(2048ull * 512 * 2);
    u16*   WcatTl= (u16*)  carve(2048ull * 512 * 2);
    u16*   WLoTh = (u16*)  carve(512ull * 512 * 2);
    u16*   WLoTl = (u16*)  carve(512ull * 512 * 2);
    u16*   WCoTh = (u16*)  carve(512ull * 512 * 2);
    u16*   WCoTl = (u16*)  carve(512ull * 512 * 2);
    u16*   WToTh = (u16*)  carve(512ull * 512 * 2);
    u16*   WToTl = (u16*)  carve(512ull * 512 * 2);
    float* bcat  = (float*)carve(2048ull * 4);
    float* comp  = (float*)carve(384ull * 512 * 4);
    float* kc    = (float*)carve(384ull * 512 * 4);
    float* vc    = (float*)carve(384ull * 512 * 4);
    float* impb  = (float*)carve(4096ull * 4);
    int*   tidx  = (int*)  carve(128ull * 4);
    float* sel   = (float*)carve(128ull * 512 * 4);
    float* kt    = (float*)carve(128ull * 512 * 4);
    float* vt    = (float*)carve(128ull * 512 * 4);
    u16*   aLh   = (u16*)  carve(4096ull * 512 * 2);
    u16*   aLl   = (u16*)  carve(4096ull * 512 * 2);
    u16*   aCh   = (u16*)  carve(4096ull * 512 * 2);
    u16*   aCl   = (u16*)  carve(4096ull * 512 * 2);
    u16*   aTh   = (u16*)  carve(4096ull * 512 * 2);
    u16*   aTl   = (u16*)  carve(4096ull * 512 * 2);

    // ---- conversions ----
    conv_act<<<1024, 256, 0, stream>>>(x, xh, xl, 4096 * 512 / 8);
    conv_wT<<<dim3(24, 8), 256, 0, stream>>>(lqkv_W, 1536, WqkvTh, WqkvTl, 0);
    conv_wT7<<<dim3(8, 8, 7), 256, 0, stream>>>(cq_W, tq_W, gc_W, gt_W, lout_W, cout_W, tout_W,
                                                WcatTh, WcatTl, WLoTh, WLoTl, WCoTh, WCoTl, WToTh, WToTl);
    bcat_fill<<<8, 256, 0, stream>>>(cq_b, tq_b, gc_b, gt_b, bcat);

    // ---- big projections via split-bf16 MFMA (128x128 tile) ----
    gemm_mfma<0><<<dim3(12, 32), 256, 0, stream>>>(xh, xl, WqkvTh, WqkvTl, lqkv_b, qkv, nullptr, 0, 1536);
    gemm_mfma<0><<<dim3(16, 32), 256, 0, stream>>>(xh, xl, WcatTh, WcatTl, bcat, fq, nullptr, 0, 2048);

    // ---- pooling + compressed K/V ----
    pool_x<<<384, 256, 0, stream>>>(x, comp);
    gemm_k512<4><<<dim3(8, 6), 256, 0, stream>>>(comp, ck_W, ck_b, kc, 384, 512);
    gemm_k512<4><<<dim3(8, 6), 256, 0, stream>>>(comp, cv_W, cv_b, vc, 384, 512);

    // ---- importance + top-k + gather + selected K/V ----
    gemv_imp<<<1024, 256, 0, stream>>>(x, imp_W, imp_b, impb);
    topk_bitonic<<<2, 1024, 0, stream>>>(impb, tidx);
    gather_sel<<<128, 256, 0, stream>>>(x, tidx, sel);
    gemm_k512<4><<<dim3(8, 2), 256, 0, stream>>>(sel, tk_W, tk_b, kt, 128, 512);
    gemm_k512<4><<<dim3(8, 2), 256, 0, stream>>>(sel, tv_W, tv_b, vt, 128, 512);

    // ---- attention: MFMA flash (split-bf16) ----
    attn_mfma<0><<<dim3(32, 8, 2), 256, 0, stream>>>(qkv, qkv, qkv, nullptr, aLh, aLl);
    attn_mfma<1><<<dim3(32, 8, 2), 256, 0, stream>>>(fq, kc, vc, nullptr, aCh, aCl);
    attn_mfma<2><<<dim3(32, 8, 2), 256, 0, stream>>>(fq, kt, vt, tidx, aTh, aTl);

    // ---- output projections: out = projL + sig(gC)*projC + sig(gT)*projT ----
    gemm_mfma<0><<<dim3(4, 32), 256, 0, stream>>>(aLh, aLl, WLoTh, WLoTl, lout_b, out, nullptr, 0, 512);
    gemm_mfma<1><<<dim3(4, 32), 256, 0, stream>>>(aCh, aCl, WCoTh, WCoTl, cout_b, out, fq + 1024, 2048, 512);
    gemm_mfma<1><<<dim3(4, 32), 256, 0, stream>>>(aTh, aTl, WToTh, WToTl, tout_b, out, fq + 1536, 2048, 512);
}

// Round 9
// 414.163 us; speedup vs baseline: 3.7278x; 1.2673x over previous
//
#include <hip/hip_runtime.h>
#include <cstdint>
#include <cstddef>

#define HNUM 8
#define HDIM 64
#define WIN 512
#define RATIO 8
#define TOPKN 64
#define BATCH 2
#define SEQ 2048
#define DM 512
#define NPOOLS 192
#define NEGV (-1000000000.0f)

typedef unsigned short u16;
typedef __attribute__((ext_vector_type(8))) short bf16x8;
typedef __attribute__((ext_vector_type(4))) float f32x4;

static __device__ __forceinline__ int imaxi(int a, int b){ return a > b ? a : b; }
static __device__ __forceinline__ int imini(int a, int b){ return a < b ? a : b; }

// bf16 round-to-nearest-even via bit ops (inputs finite)
static __device__ __forceinline__ u16 f2bf(float v) {
    union { float f; uint32_t u; } c; c.f = v;
    uint32_t r = c.u + 0x7fffu + ((c.u >> 16) & 1u);
    return (u16)(r >> 16);
}
static __device__ __forceinline__ float bf2f(u16 u) {
    union { uint32_t u; float f; } c; c.u = ((uint32_t)u) << 16;
    return c.f;
}

// ---------------- fp32 -> (hi, lo) bf16 planes, elementwise ----------------
__global__ __launch_bounds__(256)
void conv_act(const float* __restrict__ in, u16* __restrict__ h, u16* __restrict__ l, int n8)
{
    int i = blockIdx.x * 256 + threadIdx.x;
    if (i >= n8) return;
    const float4* p = (const float4*)(in + (size_t)i * 8);
    float4 a = p[0], b = p[1];
    float v[8] = {a.x, a.y, a.z, a.w, b.x, b.y, b.z, b.w};
    u16 hs[8], ls[8];
    #pragma unroll
    for (int j = 0; j < 8; ++j) {
        hs[j] = f2bf(v[j]);
        ls[j] = f2bf(v[j] - bf2f(hs[j]));
    }
    *(uint4*)(h + (size_t)i * 8) = *(uint4*)hs;
    *(uint4*)(l + (size_t)i * 8) = *(uint4*)ls;
}

// ------------- weight transpose-convert: W[512][N] -> WT planes [N][512] -------------
__global__ __launch_bounds__(256)
void conv_wT(const float* __restrict__ W, int N,
             u16* __restrict__ WTh, u16* __restrict__ WTl, int dstRowOff)
{
    __shared__ float t[64][65];
    const int n0 = blockIdx.x * 64, k0 = blockIdx.y * 64;
    const int tid = threadIdx.x;
    const int tk = tid >> 4, tn = (tid & 15) * 4;
    #pragma unroll
    for (int r = 0; r < 4; ++r) {
        int k = tk + r * 16;
        float4 v = *(const float4*)(W + (size_t)(k0 + k) * N + n0 + tn);
        t[k][tn + 0] = v.x; t[k][tn + 1] = v.y; t[k][tn + 2] = v.z; t[k][tn + 3] = v.w;
    }
    __syncthreads();
    const int nl = tid >> 2, s = tid & 3;
    u16 hs[16], ls[16];
    #pragma unroll
    for (int j = 0; j < 16; ++j) {
        float v = t[s * 16 + j][nl];
        hs[j] = f2bf(v);
        ls[j] = f2bf(v - bf2f(hs[j]));
    }
    size_t base = (size_t)(dstRowOff + n0 + nl) * 512 + k0 + s * 16;
    *(uint4*)(WTh + base)     = ((uint4*)hs)[0];
    *(uint4*)(WTh + base + 8) = ((uint4*)hs)[1];
    *(uint4*)(WTl + base)     = ((uint4*)ls)[0];
    *(uint4*)(WTl + base + 8) = ((uint4*)ls)[1];
}

// ------------- 11x (512x512) weight transpose-convert in one launch -------------
// z 0-3: cq,tq,gc,gt -> WcatT rows z*512 ; z 4-6: lout,cout,tout -> own buffers ;
// z 7-10: ck,cv,tk,tv -> WkvT rows (z-7)*512
__global__ __launch_bounds__(256)
void conv_wT11(const float* __restrict__ w0, const float* __restrict__ w1,
               const float* __restrict__ w2, const float* __restrict__ w3,
               const float* __restrict__ w4, const float* __restrict__ w5,
               const float* __restrict__ w6, const float* __restrict__ w7,
               const float* __restrict__ w8, const float* __restrict__ w9,
               const float* __restrict__ w10,
               u16* __restrict__ WcatTh, u16* __restrict__ WcatTl,
               u16* __restrict__ WLoTh, u16* __restrict__ WLoTl,
               u16* __restrict__ WCoTh, u16* __restrict__ WCoTl,
               u16* __restrict__ WToTh, u16* __restrict__ WToTl,
               u16* __restrict__ WkvTh, u16* __restrict__ WkvTl)
{
    const float* W; u16* dh; u16* dl; int rowoff = 0;
    switch (blockIdx.z) {
        case 0:  W = w0;  dh = WcatTh; dl = WcatTl; rowoff = 0;    break;
        case 1:  W = w1;  dh = WcatTh; dl = WcatTl; rowoff = 512;  break;
        case 2:  W = w2;  dh = WcatTh; dl = WcatTl; rowoff = 1024; break;
        case 3:  W = w3;  dh = WcatTh; dl = WcatTl; rowoff = 1536; break;
        case 4:  W = w4;  dh = WLoTh;  dl = WLoTl;  rowoff = 0;    break;
        case 5:  W = w5;  dh = WCoTh;  dl = WCoTl;  rowoff = 0;    break;
        case 6:  W = w6;  dh = WToTh;  dl = WToTl;  rowoff = 0;    break;
        case 7:  W = w7;  dh = WkvTh;  dl = WkvTl;  rowoff = 0;    break;
        case 8:  W = w8;  dh = WkvTh;  dl = WkvTl;  rowoff = 512;  break;
        case 9:  W = w9;  dh = WkvTh;  dl = WkvTl;  rowoff = 1024; break;
        default: W = w10; dh = WkvTh;  dl = WkvTl;  rowoff = 1536; break;
    }
    __shared__ float t[64][65];
    const int n0 = blockIdx.x * 64, k0 = blockIdx.y * 64;
    const int tid = threadIdx.x;
    const int tk = tid >> 4, tn = (tid & 15) * 4;
    #pragma unroll
    for (int r = 0; r < 4; ++r) {
        int k = tk + r * 16;
        float4 v = *(const float4*)(W + (size_t)(k0 + k) * 512 + n0 + tn);
        t[k][tn + 0] = v.x; t[k][tn + 1] = v.y; t[k][tn + 2] = v.z; t[k][tn + 3] = v.w;
    }
    __syncthreads();
    const int nl = tid >> 2, s = tid & 3;
    u16 hs[16], ls[16];
    #pragma unroll
    for (int j = 0; j < 16; ++j) {
        float v = t[s * 16 + j][nl];
        hs[j] = f2bf(v);
        ls[j] = f2bf(v - bf2f(hs[j]));
    }
    size_t base = (size_t)(rowoff + n0 + nl) * 512 + k0 + s * 16;
    *(uint4*)(dh + base)     = ((uint4*)hs)[0];
    *(uint4*)(dh + base + 8) = ((uint4*)hs)[1];
    *(uint4*)(dl + base)     = ((uint4*)ls)[0];
    *(uint4*)(dl + base + 8) = ((uint4*)ls)[1];
}

// ---------------- bias concat (4 x 512 -> 2048) ----------------
__global__ void bcat_fill(const float* __restrict__ b0, const float* __restrict__ b1,
                          const float* __restrict__ b2, const float* __restrict__ b3,
                          float* __restrict__ bcat)
{
    int i = blockIdx.x * 256 + threadIdx.x;
    if (i < 512) bcat[i] = b0[i];
    else if (i < 1024) bcat[i] = b1[i - 512];
    else if (i < 1536) bcat[i] = b2[i - 1024];
    else if (i < 2048) bcat[i] = b3[i - 1536];
}

// ---------------- split-bf16 MFMA GEMM: tile 128x128, K=512 ----------------
// MODE 0: C = A@B + bias   |   MODE 1: C += sigmoid(G) * (A@B + bias)
template<int MODE>
__global__ __launch_bounds__(256)
void gemm_mfma(const u16* __restrict__ Ah, const u16* __restrict__ Al,
               const u16* __restrict__ BTh, const u16* __restrict__ BTl,
               const float* __restrict__ bias, float* __restrict__ C,
               const float* __restrict__ G, int gstride, int N)
{
    __shared__ __align__(16) u16 AsH[128 * 40], AsL[128 * 40], BsH[128 * 40], BsL[128 * 40];
    const int tid = threadIdx.x;
    const int m0 = blockIdx.y * 128, n0 = blockIdx.x * 128;
    const int wid = tid >> 6, lane = tid & 63;
    const int wm = (wid >> 1) * 64, wn = (wid & 1) * 64;
    const int lr = lane & 15, lg = lane >> 4;

    f32x4 acc[4][4];
    #pragma unroll
    for (int i = 0; i < 4; ++i)
        #pragma unroll
        for (int j = 0; j < 4; ++j) acc[i][j] = (f32x4){0.f, 0.f, 0.f, 0.f};

    const int r0 = tid >> 2, s = tid & 3;

    for (int k0 = 0; k0 < 512; k0 += 32) {
        __syncthreads();
        size_t ga = (size_t)(m0 + r0) * 512 + k0 + s * 8;
        *(uint4*)&AsH[r0 * 40 + s * 8] = *(const uint4*)(Ah + ga);
        *(uint4*)&AsL[r0 * 40 + s * 8] = *(const uint4*)(Al + ga);
        size_t ga2 = (size_t)(m0 + r0 + 64) * 512 + k0 + s * 8;
        *(uint4*)&AsH[(r0 + 64) * 40 + s * 8] = *(const uint4*)(Ah + ga2);
        *(uint4*)&AsL[(r0 + 64) * 40 + s * 8] = *(const uint4*)(Al + ga2);
        size_t gb = (size_t)(n0 + r0) * 512 + k0 + s * 8;
        *(uint4*)&BsH[r0 * 40 + s * 8] = *(const uint4*)(BTh + gb);
        *(uint4*)&BsL[r0 * 40 + s * 8] = *(const uint4*)(BTl + gb);
        size_t gb2 = (size_t)(n0 + r0 + 64) * 512 + k0 + s * 8;
        *(uint4*)&BsH[(r0 + 64) * 40 + s * 8] = *(const uint4*)(BTh + gb2);
        *(uint4*)&BsL[(r0 + 64) * 40 + s * 8] = *(const uint4*)(BTl + gb2);
        __syncthreads();

        bf16x8 ah[4], al[4], bh[4], bl[4];
        #pragma unroll
        for (int i = 0; i < 4; ++i) {
            int row = wm + i * 16 + lr;
            ah[i] = *(const bf16x8*)&AsH[row * 40 + lg * 8];
            al[i] = *(const bf16x8*)&AsL[row * 40 + lg * 8];
        }
        #pragma unroll
        for (int j = 0; j < 4; ++j) {
            int row = wn + j * 16 + lr;
            bh[j] = *(const bf16x8*)&BsH[row * 40 + lg * 8];
            bl[j] = *(const bf16x8*)&BsL[row * 40 + lg * 8];
        }
        #pragma unroll
        for (int i = 0; i < 4; ++i)
            #pragma unroll
            for (int j = 0; j < 4; ++j) {
                acc[i][j] = __builtin_amdgcn_mfma_f32_16x16x32_bf16(ah[i], bh[j], acc[i][j], 0, 0, 0);
                acc[i][j] = __builtin_amdgcn_mfma_f32_16x16x32_bf16(ah[i], bl[j], acc[i][j], 0, 0, 0);
                acc[i][j] = __builtin_amdgcn_mfma_f32_16x16x32_bf16(al[i], bh[j], acc[i][j], 0, 0, 0);
            }
    }

    #pragma unroll
    for (int i = 0; i < 4; ++i)
        #pragma unroll
        for (int j = 0; j < 4; ++j) {
            int col = n0 + wn + j * 16 + lr;
            float bs = bias[col];
            #pragma unroll
            for (int r = 0; r < 4; ++r) {
                int row = m0 + wm + i * 16 + lg * 4 + r;
                float v = acc[i][j][r] + bs;
                size_t idx = (size_t)row * N + col;
                if (MODE == 0) C[idx] = v;
                else {
                    float g = G[(size_t)row * gstride + col];
                    C[idx] += v / (1.0f + __expf(-g));
                }
            }
        }
}

// ---------------- pool xkv cols 0..1023 -> kc (0..511), vc (512..1023) ----------------
__global__ __launch_bounds__(256)
void pool_kv(const float* __restrict__ xkv, float* __restrict__ kc, float* __restrict__ vc)
{
    int row = blockIdx.x;              // 0..383
    int b = row / NPOOLS, p = row % NPOOLS;
    const float* src = xkv + ((size_t)b * SEQ + (size_t)p * RATIO) * 2048;
    for (int d = threadIdx.x; d < 1024; d += 256) {
        float sv = 0.f;
        #pragma unroll
        for (int r = 0; r < RATIO; ++r) sv += src[(size_t)r * 2048 + d];
        sv *= 0.125f;
        if (d < 512) kc[(size_t)row * DM + d] = sv;
        else         vc[(size_t)row * DM + (d - 512)] = sv;
    }
}

// ---------------- gather xkv cols 1024..2047 at tidx rows -> kt, vt ----------------
__global__ __launch_bounds__(256)
void gather_kv(const float* __restrict__ xkv, const int* __restrict__ tidx,
               float* __restrict__ kt, float* __restrict__ vt)
{
    int j = blockIdx.x;                // 0..127
    int b = j >> 6;
    int t = tidx[j];
    const float* src = xkv + ((size_t)b * SEQ + t) * 2048 + 1024;
    for (int d = threadIdx.x; d < 512; d += 256) {
        kt[(size_t)j * DM + d] = src[d];
        vt[(size_t)j * DM + d] = src[512 + d];
    }
}

// ---------------- importance GEMV ----------------
__global__ __launch_bounds__(256)
void gemv_imp(const float* __restrict__ x, const float* __restrict__ w,
              const float* __restrict__ bsc, float* __restrict__ imp)
{
    int row = blockIdx.x * 4 + (threadIdx.x >> 6);
    int lane = threadIdx.x & 63;
    const float* xr = x + (size_t)row * DM;
    float sv = 0.f;
    #pragma unroll
    for (int i = 0; i < 8; ++i) sv += xr[lane + i * 64] * w[lane + i * 64];
    #pragma unroll
    for (int off = 32; off; off >>= 1) sv += __shfl_xor(sv, off);
    if (lane == 0) imp[row] = sv + bsc[0];
}

// ---------------- top-64 per batch via full bitonic sort (2048 elems) ----------------
__global__ __launch_bounds__(1024)
void topk_bitonic(const float* __restrict__ imp, int* __restrict__ tidx)
{
    __shared__ float v[SEQ];
    __shared__ int ix[SEQ];
    const int b = blockIdx.x, tid = threadIdx.x;
    for (int i = tid; i < SEQ; i += 1024) { v[i] = imp[(size_t)b * SEQ + i]; ix[i] = i; }
    __syncthreads();
    for (int k = 2; k <= SEQ; k <<= 1) {
        for (int j = k >> 1; j > 0; j >>= 1) {
            for (int i = tid; i < SEQ; i += 1024) {
                int l = i ^ j;
                if (l > i) {
                    float vi = v[i], vl = v[l];
                    int ii = ix[i], il = ix[l];
                    bool iAfterL = (vi < vl) || (vi == vl && ii > il);
                    if (((i & k) == 0) == iAfterL) {
                        v[i] = vl; v[l] = vi; ix[i] = il; ix[l] = ii;
                    }
                }
            }
            __syncthreads();
        }
    }
    if (tid < TOPKN) tidx[b * TOPKN + tid] = ix[tid];
}

// =====================================================================
// Attention (MFMA flash, split-bf16): block = 64 queries x 1 head;
// 4 waves x 16-query strips; K-tiles of 64 keys in LDS (stride-72 rows),
// V transposed [d][key]; P transposed through LDS (aliases K buffer).
// BRANCH: 0=local window, 1=compressed pools, 2=topk selected.
// =====================================================================
template<int BRANCH>
__global__ __launch_bounds__(256)
void attn_mfma(const float* __restrict__ Qsrc, const float* __restrict__ Ksrc,
               const float* __restrict__ Vsrc, const int* __restrict__ tidx,
               u16* __restrict__ oh, u16* __restrict__ ol)
{
    __shared__ __align__(16) u16 Kh[64 * 72], Kl[64 * 72], VTh[64 * 72], VTl[64 * 72];
    const int tid = threadIdx.x;
    const int w = tid >> 6, lane = tid & 63;
    const int lr = lane & 15, lg = lane >> 4;
    const int qb = blockIdx.x, h = blockIdx.y, b = blockIdx.z;
    const int q0 = qb * 64;
    const int qrow0 = q0 + w * 16;

    const int QSTRIDE = (BRANCH == 0) ? 1536 : 2048;
    const int qcol = (BRANCH == 2) ? 512 + h * HDIM : h * HDIM;
    const float* qrow = Qsrc + (size_t)(b * SEQ + qrow0 + lr) * QSTRIDE + qcol;
    bf16x8 Qh[2], Ql[2];
    #pragma unroll
    for (int ks = 0; ks < 2; ++ks) {
        int d0 = ks * 32 + lg * 8;
        float4 a = *(const float4*)(qrow + d0);
        float4 bq = *(const float4*)(qrow + d0 + 4);
        float v[8] = {a.x, a.y, a.z, a.w, bq.x, bq.y, bq.z, bq.w};
        u16 hs[8], ls[8];
        #pragma unroll
        for (int j = 0; j < 8; ++j) {
            float sv = v[j] * 0.125f;
            hs[j] = f2bf(sv);
            ls[j] = f2bf(sv - bf2f(hs[j]));
        }
        Qh[ks] = *(bf16x8*)hs;
        Ql[ks] = *(bf16x8*)ls;
    }

    int tj[4]; int tmin = 0x7fffffff;
    if (BRANCH == 2) {
        #pragma unroll
        for (int nf = 0; nf < 4; ++nf) {
            tj[nf] = tidx[b * TOPKN + nf * 16 + lr];
            tmin = imini(tmin, tj[nf]);
        }
        tmin = imini(tmin, __shfl_xor(tmin, 1));
        tmin = imini(tmin, __shfl_xor(tmin, 2));
        tmin = imini(tmin, __shfl_xor(tmin, 4));
        tmin = imini(tmin, __shfl_xor(tmin, 8));
    }

    int t0 = 0, t1 = 0;
    if (BRANCH == 0) { t0 = imaxi(0, qb - 8); t1 = qb; }
    else if (BRANCH == 1) { t0 = 0; t1 = (qb == 0) ? 2 : imini(2, (qb * 8 + 6) >> 6); }

    f32x4 onf[4];
    #pragma unroll
    for (int i = 0; i < 4; ++i) onf[i] = (f32x4){0.f, 0.f, 0.f, 0.f};
    f32x4 lvec = (f32x4){0.f, 0.f, 0.f, 0.f};

    const int r_ = tid >> 2, c4 = tid & 3;
    const int dd = tid >> 2, k4 = (tid & 3) * 16;

    for (int t = t0; t <= t1; ++t) {
        const int kb = t * 64;
        __syncthreads();

        {
            const float* kr;
            if (BRANCH == 0)
                kr = Ksrc + (size_t)(b * SEQ + kb + r_) * 1536 + 512 + h * HDIM + c4 * 16;
            else if (BRANCH == 1)
                kr = Ksrc + (size_t)(b * NPOOLS + kb + r_) * DM + h * HDIM + c4 * 16;
            else
                kr = Ksrc + (size_t)(b * TOPKN + r_) * DM + h * HDIM + c4 * 16;
            float vv[16];
            #pragma unroll
            for (int j4 = 0; j4 < 4; ++j4)
                *(float4*)(&vv[j4 * 4]) = *(const float4*)(kr + j4 * 4);
            u16 hs[16], ls[16];
            #pragma unroll
            for (int j = 0; j < 16; ++j) {
                hs[j] = f2bf(vv[j]);
                ls[j] = f2bf(vv[j] - bf2f(hs[j]));
            }
            *(uint4*)&Kh[r_ * 72 + c4 * 16]     = ((uint4*)hs)[0];
            *(uint4*)&Kh[r_ * 72 + c4 * 16 + 8] = ((uint4*)hs)[1];
            *(uint4*)&Kl[r_ * 72 + c4 * 16]     = ((uint4*)ls)[0];
            *(uint4*)&Kl[r_ * 72 + c4 * 16 + 8] = ((uint4*)ls)[1];
        }
        {
            const float* vb;
            int RS;
            if (BRANCH == 0) { vb = Vsrc + (size_t)(b * SEQ + kb + k4) * 1536 + 1024 + h * HDIM + dd; RS = 1536; }
            else if (BRANCH == 1) { vb = Vsrc + (size_t)(b * NPOOLS + kb + k4) * DM + h * HDIM + dd; RS = DM; }
            else { vb = Vsrc + (size_t)(b * TOPKN + k4) * DM + h * HDIM + dd; RS = DM; }
            u16 hs[16], ls[16];
            #pragma unroll
            for (int j = 0; j < 16; ++j) {
                float v = vb[(size_t)j * RS];
                hs[j] = f2bf(v);
                ls[j] = f2bf(v - bf2f(hs[j]));
            }
            *(uint4*)&VTh[dd * 72 + k4]     = ((uint4*)hs)[0];
            *(uint4*)&VTh[dd * 72 + k4 + 8] = ((uint4*)hs)[1];
            *(uint4*)&VTl[dd * 72 + k4]     = ((uint4*)ls)[0];
            *(uint4*)&VTl[dd * 72 + k4 + 8] = ((uint4*)ls)[1];
        }
        __syncthreads();

        f32x4 sf[4];
        #pragma unroll
        for (int nf = 0; nf < 4; ++nf) {
            sf[nf] = (f32x4){0.f, 0.f, 0.f, 0.f};
            #pragma unroll
            for (int ks = 0; ks < 2; ++ks) {
                bf16x8 bh = *(const bf16x8*)&Kh[(nf * 16 + lr) * 72 + ks * 32 + lg * 8];
                bf16x8 bl = *(const bf16x8*)&Kl[(nf * 16 + lr) * 72 + ks * 32 + lg * 8];
                sf[nf] = __builtin_amdgcn_mfma_f32_16x16x32_bf16(Qh[ks], bh, sf[nf], 0, 0, 0);
                sf[nf] = __builtin_amdgcn_mfma_f32_16x16x32_bf16(Qh[ks], bl, sf[nf], 0, 0, 0);
                sf[nf] = __builtin_amdgcn_mfma_f32_16x16x32_bf16(Ql[ks], bh, sf[nf], 0, 0, 0);
            }
        }
        __syncthreads();

        u16* Ph = Kh + w * 1152;
        u16* Pl = Kl + w * 1152;
        #pragma unroll
        for (int nf = 0; nf < 4; ++nf) {
            #pragma unroll
            for (int rr = 0; rr < 4; ++rr) {
                int rq = qrow0 + lg * 4 + rr;
                int ck = kb + nf * 16 + lr;
                float s = sf[nf][rr];
                float p;
                if (BRANCH == 0) {
                    bool valid = (ck <= rq) && (rq - ck < WIN);
                    p = valid ? __expf(s) : 0.f;
                } else if (BRANCH == 1) {
                    bool valid = rq >= (ck + 1) * RATIO;
                    p = (rq < RATIO) ? 1.f : (valid ? __expf(s) : 0.f);
                } else {
                    bool valid = rq >= tj[nf];
                    p = (rq < tmin) ? 1.f : (valid ? __expf(s) : 0.f);
                }
                lvec[rr] += p;
                u16 ph_ = f2bf(p);
                Ph[(lg * 4 + rr) * 72 + nf * 16 + lr] = ph_;
                Pl[(lg * 4 + rr) * 72 + nf * 16 + lr] = f2bf(p - bf2f(ph_));
            }
        }

        bf16x8 pah[2], pal[2];
        #pragma unroll
        for (int ks2 = 0; ks2 < 2; ++ks2) {
            pah[ks2] = *(const bf16x8*)&Ph[lr * 72 + ks2 * 32 + lg * 8];
            pal[ks2] = *(const bf16x8*)&Pl[lr * 72 + ks2 * 32 + lg * 8];
        }
        #pragma unroll
        for (int nd = 0; nd < 4; ++nd) {
            #pragma unroll
            for (int ks2 = 0; ks2 < 2; ++ks2) {
                bf16x8 vh = *(const bf16x8*)&VTh[(nd * 16 + lr) * 72 + ks2 * 32 + lg * 8];
                bf16x8 vl = *(const bf16x8*)&VTl[(nd * 16 + lr) * 72 + ks2 * 32 + lg * 8];
                onf[nd] = __builtin_amdgcn_mfma_f32_16x16x32_bf16(pah[ks2], vh, onf[nd], 0, 0, 0);
                onf[nd] = __builtin_amdgcn_mfma_f32_16x16x32_bf16(pah[ks2], vl, onf[nd], 0, 0, 0);
                onf[nd] = __builtin_amdgcn_mfma_f32_16x16x32_bf16(pal[ks2], vh, onf[nd], 0, 0, 0);
            }
        }
    }

    #pragma unroll
    for (int bit = 1; bit <= 8; bit <<= 1) {
        lvec[0] += __shfl_xor(lvec[0], bit);
        lvec[1] += __shfl_xor(lvec[1], bit);
        lvec[2] += __shfl_xor(lvec[2], bit);
        lvec[3] += __shfl_xor(lvec[3], bit);
    }
    f32x4 inv;
    #pragma unroll
    for (int rr = 0; rr < 4; ++rr) inv[rr] = 1.0f / lvec[rr];

    #pragma unroll
    for (int nd = 0; nd < 4; ++nd) {
        #pragma unroll
        for (int rr = 0; rr < 4; ++rr) {
            int row = b * SEQ + qrow0 + lg * 4 + rr;
            size_t idx = (size_t)row * DM + h * HDIM + nd * 16 + lr;
            float v = onf[nd][rr] * inv[rr];
            u16 hv = f2bf(v);
            oh[idx] = hv;
            ol[idx] = f2bf(v - bf2f(hv));
        }
    }
}

extern "C" void kernel_launch(void* const* d_in, const int* in_sizes, int n_in,
                              void* d_out, int out_size, void* d_ws, size_t ws_size,
                              hipStream_t stream)
{
    const float* x      = (const float*)d_in[0];
    const float* lqkv_W = (const float*)d_in[1];
    const float* lqkv_b = (const float*)d_in[2];
    const float* lout_W = (const float*)d_in[3];
    const float* lout_b = (const float*)d_in[4];
    const float* cq_W   = (const float*)d_in[5];
    const float* cq_b   = (const float*)d_in[6];
    const float* ck_W   = (const float*)d_in[7];
    const float* ck_b   = (const float*)d_in[8];
    const float* cv_W   = (const float*)d_in[9];
    const float* cv_b   = (const float*)d_in[10];
    const float* cout_W = (const float*)d_in[11];
    const float* cout_b = (const float*)d_in[12];
    const float* gc_W   = (const float*)d_in[13];
    const float* gc_b   = (const float*)d_in[14];
    const float* imp_W  = (const float*)d_in[15];
    const float* imp_b  = (const float*)d_in[16];
    const float* tq_W   = (const float*)d_in[17];
    const float* tq_b   = (const float*)d_in[18];
    const float* tk_W   = (const float*)d_in[19];
    const float* tk_b   = (const float*)d_in[20];
    const float* tv_W   = (const float*)d_in[21];
    const float* tv_b   = (const float*)d_in[22];
    const float* tout_W = (const float*)d_in[23];
    const float* tout_b = (const float*)d_in[24];
    const float* gt_W   = (const float*)d_in[25];
    const float* gt_b   = (const float*)d_in[26];
    float* out = (float*)d_out;

    char* wsb = (char*)d_ws;
    size_t off = 0;
    auto carve = [&](size_t bytes) { void* p = wsb + off; off += (bytes + 255) & ~(size_t)255; return p; };
    float* qkv   = (float*)carve(4096ull * 1536 * 4);
    float* fq    = (float*)carve(4096ull * 2048 * 4);
    // region X: xkv (fp32, 4096x2048) aliased by the attention-output planes.
    // xkv is fully consumed by pool_kv/gather_kv BEFORE any attn_mfma launch
    // (same-stream serialization) -> safe to overlay.
    char*  X     = (char*) carve(4096ull * 2048 * 4);
    float* xkv   = (float*)X;
    u16*   aLh   = (u16*)(X);
    u16*   aLl   = (u16*)(X + 1 * 4194304);
    u16*   aCh   = (u16*)(X + 2 * 4194304);
    u16*   aCl   = (u16*)(X + 3 * 4194304);
    u16*   aTh   = (u16*)(X + 4 * 4194304);
    u16*   aTl   = (u16*)(X + 5 * 4194304);
    u16*   xh    = (u16*)  carve(4096ull * 512 * 2);
    u16*   xl    = (u16*)  carve(4096ull * 512 * 2);
    u16*   WqkvTh= (u16*)  carve(1536ull * 512 * 2);
    u16*   WqkvTl= (u16*)  carve(1536ull * 512 * 2);
    u16*   WcatTh= (u16*)  carve(2048ull * 512 * 2);
    u16*   WcatTl= (u16*)  carve(2048ull * 512 * 2);
    u16*   WkvTh = (u16*)  carve(2048ull * 512 * 2);
    u16*   WkvTl = (u16*)  carve(2048ull * 512 * 2);
    u16*   WLoTh = (u16*)  carve(512ull * 512 * 2);
    u16*   WLoTl = (u16*)  carve(512ull * 512 * 2);
    u16*   WCoTh = (u16*)  carve(512ull * 512 * 2);
    u16*   WCoTl = (u16*)  carve(512ull * 512 * 2);
    u16*   WToTh = (u16*)  carve(512ull * 512 * 2);
    u16*   WToTl = (u16*)  carve(512ull * 512 * 2);
    float* bcat  = (float*)carve(2048ull * 4);
    float* bkv   = (float*)carve(2048ull * 4);
    float* kc    = (float*)carve(384ull * 512 * 4);
    float* vc    = (float*)carve(384ull * 512 * 4);
    float* impb  = (float*)carve(4096ull * 4);
    int*   tidx  = (int*)  carve(128ull * 4);
    float* kt    = (float*)carve(128ull * 512 * 4);
    float* vt    = (float*)carve(128ull * 512 * 4);

    // ---- conversions ----
    conv_act<<<1024, 256, 0, stream>>>(x, xh, xl, 4096 * 512 / 8);
    conv_wT<<<dim3(24, 8), 256, 0, stream>>>(lqkv_W, 1536, WqkvTh, WqkvTl, 0);
    conv_wT11<<<dim3(8, 8, 11), 256, 0, stream>>>(cq_W, tq_W, gc_W, gt_W, lout_W, cout_W, tout_W,
                                                  ck_W, cv_W, tk_W, tv_W,
                                                  WcatTh, WcatTl, WLoTh, WLoTl, WCoTh, WCoTl,
                                                  WToTh, WToTl, WkvTh, WkvTl);
    bcat_fill<<<8, 256, 0, stream>>>(cq_b, tq_b, gc_b, gt_b, bcat);
    bcat_fill<<<8, 256, 0, stream>>>(ck_b, cv_b, tk_b, tv_b, bkv);

    // ---- big projections via split-bf16 MFMA (128x128 tile) ----
    gemm_mfma<0><<<dim3(12, 32), 256, 0, stream>>>(xh, xl, WqkvTh, WqkvTl, lqkv_b, qkv, nullptr, 0, 1536);
    gemm_mfma<0><<<dim3(16, 32), 256, 0, stream>>>(xh, xl, WkvTh, WkvTl, bkv, xkv, nullptr, 0, 2048);

    // ---- importance + top-k (overlap with xkv consumers' prerequisites) ----
    gemv_imp<<<1024, 256, 0, stream>>>(x, imp_W, imp_b, impb);
    topk_bitonic<<<2, 1024, 0, stream>>>(impb, tidx);

    // ---- derive kc/vc (pool) and kt/vt (gather) from xkv ----
    pool_kv<<<384, 256, 0, stream>>>(xkv, kc, vc);
    gather_kv<<<128, 256, 0, stream>>>(xkv, tidx, kt, vt);

    // ---- fused q/gates projection ----
    gemm_mfma<0><<<dim3(16, 32), 256, 0, stream>>>(xh, xl, WcatTh, WcatTl, bcat, fq, nullptr, 0, 2048);

    // ---- attention: MFMA flash (split-bf16); writes a* planes into region X ----
    attn_mfma<0><<<dim3(32, 8, 2), 256, 0, stream>>>(qkv, qkv, qkv, nullptr, aLh, aLl);
    attn_mfma<1><<<dim3(32, 8, 2), 256, 0, stream>>>(fq, kc, vc, nullptr, aCh, aCl);
    attn_mfma<2><<<dim3(32, 8, 2), 256, 0, stream>>>(fq, kt, vt, tidx, aTh, aTl);

    // ---- output projections: out = projL + sig(gC)*projC + sig(gT)*projT ----
    gemm_mfma<0><<<dim3(4, 32), 256, 0, stream>>>(aLh, aLl, WLoTh, WLoTl, lout_b, out, nullptr, 0, 512);
    gemm_mfma<1><<<dim3(4, 32), 256, 0, stream>>>(aCh, aCl, WCoTh, WCoTl, cout_b, out, fq + 1024, 2048, 512);
    gemm_mfma<1><<<dim3(4, 32), 256, 0, stream>>>(aTh, aTl, WToTh, WToTl, tout_b, out, fq + 1536, 2048, 512);
}